// Round 12
// baseline (483.468 us; speedup 1.0000x reference)
//
#include <hip/hip_runtime.h>
#include <hip/hip_bf16.h>
#include <math.h>

#define N_SEQ  4096
#define DMODEL 320
#define NHEADS 8
#define DHEAD  40
#define CTXN   77
#define CTXD   768
#define FFI    1280

typedef short s8v __attribute__((ext_vector_type(8)));
typedef short s4v __attribute__((ext_vector_type(4)));
typedef float f4v __attribute__((ext_vector_type(4)));
typedef unsigned short u16;

static __device__ __forceinline__ u16 bf16u(float x) {           // RNE
    unsigned u = __float_as_uint(x);
    return (u16)((u + 0x7FFFu + ((u >> 16) & 1u)) >> 16);
}
static __device__ __forceinline__ float b2f(u16 v) { return __uint_as_float((unsigned)v << 16); }
static __device__ __forceinline__ unsigned pack2(float a, float b) {
    return (unsigned)bf16u(a) | ((unsigned)bf16u(b) << 16);
}

// async global->LDS, 16B per lane; LDS dest = wave-uniform base + lane*16 (linear)
#define GLD_LDS16(gp, lp) __builtin_amdgcn_global_load_lds( \
    (const __attribute__((address_space(1))) void*)(gp),    \
    (__attribute__((address_space(3))) void*)(lp), 16, 0, 0)

// ---------------- weight pre-convert v2: coalesced tiled transpose ----------------
struct WC { const float* s; u16* d; int K, O, trans; };
struct WCs { WC a[12]; };
__global__ __launch_bounds__(256) void wcast2_k(WCs P) {
    __shared__ float tile[32][33];
    WC w = P.a[blockIdx.y];
    if (w.trans) {
        int ntk = w.K >> 5, nto = w.O >> 5;
        int tid = blockIdx.x;
        if (tid >= ntk * nto) return;
        int tk = tid % ntk, to = tid / ntk;
        int lr = threadIdx.x >> 5, lc = threadIdx.x & 31;
#pragma unroll
        for (int p = 0; p < 4; ++p) {
            int k = tk * 32 + p * 8 + lr;
            tile[p * 8 + lr][lc] = w.s[(size_t)k * w.O + to * 32 + lc];
        }
        __syncthreads();
#pragma unroll
        for (int p = 0; p < 4; ++p) {
            int o = to * 32 + p * 8 + lr;
            w.d[(size_t)o * w.K + tk * 32 + lc] = bf16u(tile[lc][p * 8 + lr]);
        }
    } else {
        int nel = w.K * w.O;
        for (int e = blockIdx.x * 256 + threadIdx.x; e < nel; e += gridDim.x * 256)
            w.d[e] = bf16u(w.s[e]);
    }
}

// ---------------- GroupNorm stats v2: 2-stage reduction (256 blocks, float4 loads) ----------------
__global__ __launch_bounds__(256) void gn_part_k(const float* __restrict__ x, float* __restrict__ part) {
    __shared__ float red[128];
    const int b = blockIdx.x;
    const int g = b >> 3, ch = b & 7;
    const float4* xp = (const float4*)(x + (size_t)g * 40960) + ch * 1280;
    float s = 0.f, ss = 0.f;
#pragma unroll
    for (int i = 0; i < 5; ++i) {
        float4 v = xp[threadIdx.x + 256 * i];
        s  += v.x + v.y + v.z + v.w;
        ss += v.x * v.x + v.y * v.y + v.z * v.z + v.w * v.w;
    }
    for (int o = 32; o > 0; o >>= 1) { s += __shfl_xor(s, o); ss += __shfl_xor(ss, o); }
    const int w = threadIdx.x >> 6, l = threadIdx.x & 63;
    if (l == 0) { red[w] = s; red[64 + w] = ss; }
    __syncthreads();
    if (threadIdx.x == 0) {
        part[b * 2]     = red[0] + red[1] + red[2] + red[3];
        part[b * 2 + 1] = red[64] + red[65] + red[66] + red[67];
    }
}
__global__ __launch_bounds__(320) void gn_fin_k(const float* __restrict__ part,
                                                const float* __restrict__ gw, const float* __restrict__ gb,
                                                float* __restrict__ sc, float* __restrict__ sh) {
    __shared__ float ms[32][2];
    const int t = threadIdx.x;
    if (t < 32) {
        float s = 0.f, ss = 0.f;
#pragma unroll
        for (int ch = 0; ch < 8; ++ch) { s += part[(t * 8 + ch) * 2]; ss += part[(t * 8 + ch) * 2 + 1]; }
        float mean = s * (1.f / 40960.f);
        float var  = ss * (1.f / 40960.f) - mean * mean;
        ms[t][0] = mean; ms[t][1] = rsqrtf(var + 1e-6f);
    }
    __syncthreads();
    if (t < 320) {
        int g = t / 10;
        float scv = gw[t] * ms[g][1];
        sc[t] = scv;
        sh[t] = gb[t] - ms[g][0] * scv;
    }
}

struct GArg { const u16* Wt; const float* bias; float* outf; u16* outb; int ob_mode; };
#define GP 72
// attn scale * log2e, folded into Q at the qkv epilogue (self-attn exp2f takes S directly)
#define QSCALE 0.22811012f

// ---------------- gemm_t<SITE>: 64x64 tile, K-chunk 64, reg-prefetch A + async W (global_load_lds) ----
// stat != nullptr: epilogue accumulates per-row (sum, sumsq) of the final h values via atomics
// (replaces the standalone ln_stats pass). a_mode 3 reads those sums (mu[2n],mu[2n+1]) and derives
// mean/rsqrt inline in staging.
template<int SITE>
__global__ __launch_bounds__(256) void gemm_t(const void* __restrict__ Av, int a_mode, int lda,
                                              const float* __restrict__ mu, const float* __restrict__ rs,
                                              const float* __restrict__ cw, const float* __restrict__ cb,
                                              GArg g0, GArg g1, GArg g2,
                                              const float* __restrict__ res, float* __restrict__ stat,
                                              int Mrows, int K, int Oout, int obT_stride) {
    __shared__ __align__(16) u16 As[2][64 * GP];
    __shared__ __align__(16) u16 Wsm[2][64 * 64];
    const int t = threadIdx.x;
    const int w = t >> 6, lane = t & 63, c = lane & 15, quad = lane >> 4;
    const int o0 = blockIdx.x * 64, n0 = blockIdx.y * 64;
    GArg g = (blockIdx.z == 0) ? g0 : ((blockIdx.z == 1) ? g1 : g2);
    const f4v zero = {0.f, 0.f, 0.f, 0.f};
    f4v acc[4] = {zero, zero, zero, zero};
    const s8v z8 = {0, 0, 0, 0, 0, 0, 0, 0};
    const int nk = K >> 6;

    float fA[16];
    s8v bA0 = z8, bA1 = z8;

    // W source pointers: lane covers row o0 + w*16 + kk*8 + (l>>3), swizzled col
    const u16* gW0 = g.Wt + (size_t)(o0 + w * 16 + (lane >> 3)) * K + ((lane & 7) ^ (lane >> 3)) * 8;
    const u16* gW1 = gW0 + (size_t)8 * K;
    const int wdst = w * 1024;                 // u16 offset of this wave's W region
    const int swb0 = 8 * (quad ^ (c & 7));     // B-frag col (swizzled), half 0
    const int swb1 = 8 * ((quad + 4) ^ (c & 7)); // half 1 (+32 logical)

    auto gllW = [&](int b) {
        GLD_LDS16(gW0, &Wsm[b][wdst]);
        GLD_LDS16(gW1, &Wsm[b][wdst + 512]);
        gW0 += 64; gW1 += 64;
    };
    auto loadA = [&](int k0) {
        if (a_mode == 0) {
            const u16* A = (const u16*)Av;
            int i0 = t, i1 = t + 256;
            int nA = n0 + (i0 >> 3), nB = n0 + (i1 >> 3);
            bA0 = (nA < Mrows) ? *(const s8v*)(A + (size_t)nA * lda + k0 + (i0 & 7) * 8) : z8;
            bA1 = (nB < Mrows) ? *(const s8v*)(A + (size_t)nB * lda + k0 + (i1 & 7) * 8) : z8;
        } else if (a_mode == 1) {
            const float* A = (const float*)Av;
            int r = t >> 2, s16 = (t & 3) * 16;
            int n = n0 + r;
            if (n < Mrows) {
                const float* src = A + (size_t)n * lda + k0 + s16;
#pragma unroll
                for (int i = 0; i < 16; ++i) fA[i] = src[i];
            } else {
#pragma unroll
                for (int i = 0; i < 16; ++i) fA[i] = 0.f;
            }
        } else if (a_mode == 2) {
            const float* A = (const float*)Av;
#pragma unroll
            for (int j = 0; j < 16; ++j) {
                int e = t + 256 * j; int nn = e & 63, kk = e >> 6;
                int n = n0 + nn, kgl = k0 + kk;
                fA[j] = (n < Mrows) ? A[(size_t)kgl * lda + n] * cw[kgl] + cb[kgl] : 0.f;
            }
        } else if (a_mode == 3) {
            const float* A = (const float*)Av;
            int r = t >> 2, s16 = (t & 3) * 16;
            int n = n0 + r;
            if (n < Mrows) {
                const float* src = A + (size_t)n * lda + k0 + s16;
                const float* cwp = cw + k0 + s16;
                const float* cbp = cb + k0 + s16;
                float sv = mu[2 * n], qv = mu[2 * n + 1];
                float m_ = sv * (1.f / 320.f);
                float rr = rsqrtf(qv * (1.f / 320.f) - m_ * m_ + 1e-5f);
#pragma unroll
                for (int i = 0; i < 16; ++i) fA[i] = (src[i] - m_) * rr * cwp[i] + cbp[i];
            } else {
#pragma unroll
                for (int i = 0; i < 16; ++i) fA[i] = 0.f;
            }
        } else {   // 4: 2-split attention combine
            const u16* Op = (const u16*)Av;
            const float* lp = mu;
            int r = t >> 2, s16 = (t & 3) * 16;
            int n = n0 + r;
            int ch0 = k0 + s16;
            int hdA = ch0 / 40;
            int hdB = (ch0 + 15) / 40;
            float invA = 1.f / (lp[(size_t)hdA * N_SEQ + n] + lp[(size_t)(8 + hdA) * N_SEQ + n]);
            float invB = (hdB == hdA) ? invA
                       : 1.f / (lp[(size_t)hdB * N_SEQ + n] + lp[(size_t)(8 + hdB) * N_SEQ + n]);
#pragma unroll
            for (int i = 0; i < 16; ++i) {
                int ch = ch0 + i;
                int hd = ch / 40;
                int d  = ch - hd * 40;
                float num = b2f(Op[((size_t)hd * N_SEQ + n) * DHEAD + d])
                          + b2f(Op[((size_t)(8 + hd) * N_SEQ + n) * DHEAD + d]);
                fA[i] = num * ((hd == hdA) ? invA : invB);
            }
        }
    };
    auto storeA = [&](int b) {
        if (a_mode == 0) {
            int i0 = t, i1 = t + 256;
            *(s8v*)&As[b][(i0 >> 3) * GP + (i0 & 7) * 8] = bA0;
            *(s8v*)&As[b][(i1 >> 3) * GP + (i1 & 7) * 8] = bA1;
        } else if (a_mode == 2) {
#pragma unroll
            for (int j = 0; j < 16; ++j) {
                int e = t + 256 * j; int nn = e & 63, kk = e >> 6;
                As[b][nn * GP + kk] = bf16u(fA[j]);
            }
        } else {
            int r = t >> 2, s16 = (t & 3) * 16;
            unsigned* dst = (unsigned*)&As[b][r * GP + s16];
#pragma unroll
            for (int i = 0; i < 8; ++i) dst[i] = pack2(fA[2 * i], fA[2 * i + 1]);
        }
    };

    // pipeline with double buffer: one barrier per chunk
    gllW(0); loadA(0);
    storeA(0);
    __syncthreads();
    for (int k = 0; k < nk; ++k) {
        const int cur = k & 1;
        if (k + 1 < nk) { gllW(1 - cur); loadA((k + 1) << 6); }
        s8v a0 = *(const s8v*)&As[cur][(w * 16 + c) * GP + quad * 8];
        s8v a1 = *(const s8v*)&As[cur][(w * 16 + c) * GP + 32 + quad * 8];
#pragma unroll
        for (int nt = 0; nt < 4; ++nt) {
            s8v b0 = *(const s8v*)&Wsm[cur][(nt * 16 + c) * 64 + swb0];
            s8v b1 = *(const s8v*)&Wsm[cur][(nt * 16 + c) * 64 + swb1];
            acc[nt] = __builtin_amdgcn_mfma_f32_16x16x32_bf16(a0, b0, acc[nt], 0, 0, 0);
            acc[nt] = __builtin_amdgcn_mfma_f32_16x16x32_bf16(a1, b1, acc[nt], 0, 0, 0);
        }
        if (k + 1 < nk) { storeA(1 - cur); }
        __syncthreads();
    }
    // ---------- epilogue ----------
    float rsum[4] = {0.f, 0.f, 0.f, 0.f}, rsq[4] = {0.f, 0.f, 0.f, 0.f};
#pragma unroll
    for (int nt = 0; nt < 4; ++nt) {
        int o = o0 + nt * 16 + c;
        float vv[4];
#pragma unroll
        for (int r = 0; r < 4; ++r) vv[r] = acc[nt][r] + (g.bias ? g.bias[o] : 0.f);
        if (g.ob_mode == 3) {
            int nb = n0 + w * 16 + quad * 4;
            const float4 x4 = *(const float4*)(res + (size_t)o * obT_stride + nb);
            float4 o4 = make_float4(vv[0] + x4.x, vv[1] + x4.y, vv[2] + x4.z, vv[3] + x4.w);
            *(float4*)(g.outf + (size_t)o * obT_stride + nb) = o4;
        } else if (g.ob_mode == 4) {
#pragma unroll
            for (int r = 0; r < 4; ++r) {
                int n = n0 + w * 16 + quad * 4 + r;
                float vvv = vv[r];
                if (o < 320) vvv *= QSCALE;          // fold attn scale*log2e into Q
                u16 bv = bf16u(vvv);
                if (o < 320)      g0.outb[(size_t)n * 320 + o] = bv;
                else if (o < 640) g1.outb[(size_t)n * 320 + (o - 320)] = bv;
                else              g2.outb[(size_t)(o - 640) * obT_stride + n] = bv;
            }
        } else {
#pragma unroll
            for (int r = 0; r < 4; ++r) {
                int n = n0 + w * 16 + quad * 4 + r;
                if (n >= Mrows) continue;
                float v = vv[r];
                if (res) v += res[(size_t)n * Oout + o];
                if (g.outf) g.outf[(size_t)n * Oout + o] = v;
                if (g.ob_mode == 1) g.outb[(size_t)n * Oout + o] = bf16u(v);
                else if (g.ob_mode == 2) g.outb[(size_t)o * obT_stride + n] = bf16u(v);
                if (stat) { rsum[r] += v; rsq[r] += v * v; }
            }
        }
    }
    if (stat) {   // fused LN stats: reduce this block's 64 cols per row, atomically fold across o-tiles
#pragma unroll
        for (int r = 0; r < 4; ++r) {
            float s = rsum[r], q = rsq[r];
            s += __shfl_xor(s, 8); q += __shfl_xor(q, 8);
            s += __shfl_xor(s, 4); q += __shfl_xor(q, 4);
            s += __shfl_xor(s, 2); q += __shfl_xor(q, 2);
            s += __shfl_xor(s, 1); q += __shfl_xor(q, 1);
            if (c == 0) {
                int n = n0 + w * 16 + quad * 4 + r;
                atomicAdd(&stat[2 * n], s);
                atomicAdd(&stat[2 * n + 1], q);
            }
        }
    }
}

// ---------------- gemm_gg: ff1 GEGLU (LN-from-stats staging), single-buffer pipeline ---------
__global__ __launch_bounds__(256) void gemm_gg(const float* __restrict__ A, int lda,
                                               const float* __restrict__ mu, const float* __restrict__ rs,
                                               const float* __restrict__ cw, const float* __restrict__ cb,
                                               const u16* __restrict__ Wt, const float* __restrict__ bias,
                                               u16* __restrict__ outb,
                                               int K, int Oout, int geglu_off) {
    __shared__ __align__(16) u16 As[64 * GP];
    __shared__ __align__(16) u16 Wsm[64 * GP];
    __shared__ __align__(16) u16 Wgm[64 * GP];
    const int t = threadIdx.x;
    const int w = t >> 6, lane = t & 63, c = lane & 15, quad = lane >> 4;
    const int o0 = blockIdx.x * 64, n0 = blockIdx.y * 64;
    const f4v zero = {0.f, 0.f, 0.f, 0.f};
    f4v acc[4]  = {zero, zero, zero, zero};
    f4v accg[4] = {zero, zero, zero, zero};
    const int nk = K >> 6;

    float fA[16];
    s8v wv0, wv1, gv0, gv1;

    auto loadWG = [&](int k0) {
        int i0 = t, i1 = t + 256;
        wv0 = *(const s8v*)(Wt + (size_t)(o0 + (i0 >> 3)) * K + k0 + (i0 & 7) * 8);
        wv1 = *(const s8v*)(Wt + (size_t)(o0 + (i1 >> 3)) * K + k0 + (i1 & 7) * 8);
        gv0 = *(const s8v*)(Wt + (size_t)(o0 + (i0 >> 3) + geglu_off) * K + k0 + (i0 & 7) * 8);
        gv1 = *(const s8v*)(Wt + (size_t)(o0 + (i1 >> 3) + geglu_off) * K + k0 + (i1 & 7) * 8);
    };
    auto storeWG = [&]() {
        int i0 = t, i1 = t + 256;
        *(s8v*)&Wsm[(i0 >> 3) * GP + (i0 & 7) * 8] = wv0;
        *(s8v*)&Wsm[(i1 >> 3) * GP + (i1 & 7) * 8] = wv1;
        *(s8v*)&Wgm[(i0 >> 3) * GP + (i0 & 7) * 8] = gv0;
        *(s8v*)&Wgm[(i1 >> 3) * GP + (i1 & 7) * 8] = gv1;
    };
    auto loadA = [&](int k0) {
        int r = t >> 2, s16 = (t & 3) * 16;
        int n = n0 + r;
        const float* src = A + (size_t)n * lda + k0 + s16;
        const float* cwp = cw + k0 + s16;
        const float* cbp = cb + k0 + s16;
        float sv = mu[2 * n], qv = mu[2 * n + 1];
        float m_ = sv * (1.f / 320.f);
        float rr = rsqrtf(qv * (1.f / 320.f) - m_ * m_ + 1e-5f);
#pragma unroll
        for (int i = 0; i < 16; ++i) fA[i] = (src[i] - m_) * rr * cwp[i] + cbp[i];
    };
    auto storeA = [&]() {
        int r = t >> 2, s16 = (t & 3) * 16;
        unsigned* dst = (unsigned*)&As[r * GP + s16];
#pragma unroll
        for (int i = 0; i < 8; ++i) dst[i] = pack2(fA[2 * i], fA[2 * i + 1]);
    };

    loadA(0); loadWG(0);
    storeA(); storeWG();
    __syncthreads();
    for (int k = 0; k < nk; ++k) {
        if (k + 1 < nk) { loadA((k + 1) << 6); loadWG((k + 1) << 6); }
        s8v a0 = *(const s8v*)&As[(w * 16 + c) * GP + quad * 8];
        s8v a1 = *(const s8v*)&As[(w * 16 + c) * GP + 32 + quad * 8];
#pragma unroll
        for (int nt = 0; nt < 4; ++nt) {
            s8v b0 = *(const s8v*)&Wsm[(nt * 16 + c) * GP + quad * 8];
            s8v b1 = *(const s8v*)&Wsm[(nt * 16 + c) * GP + 32 + quad * 8];
            acc[nt] = __builtin_amdgcn_mfma_f32_16x16x32_bf16(a0, b0, acc[nt], 0, 0, 0);
            acc[nt] = __builtin_amdgcn_mfma_f32_16x16x32_bf16(a1, b1, acc[nt], 0, 0, 0);
            s8v q0 = *(const s8v*)&Wgm[(nt * 16 + c) * GP + quad * 8];
            s8v q1 = *(const s8v*)&Wgm[(nt * 16 + c) * GP + 32 + quad * 8];
            accg[nt] = __builtin_amdgcn_mfma_f32_16x16x32_bf16(a0, q0, accg[nt], 0, 0, 0);
            accg[nt] = __builtin_amdgcn_mfma_f32_16x16x32_bf16(a1, q1, accg[nt], 0, 0, 0);
        }
        __syncthreads();
        if (k + 1 < nk) {
            storeA(); storeWG();
            __syncthreads();
        }
    }
#pragma unroll
    for (int nt = 0; nt < 4; ++nt) {
        int o = o0 + nt * 16 + c;
#pragma unroll
        for (int r = 0; r < 4; ++r) {
            int n = n0 + w * 16 + quad * 4 + r;
            float v = acc[nt][r] + bias[o];
            float gg = accg[nt][r] + bias[o + geglu_off];
            v = v * 0.5f * gg * (1.f + erff(gg * 0.70710678118654752f));
            outb[(size_t)n * Oout + o] = bf16u(v);
        }
    }
}

// ---------------- Self-attention v10b: 128-row Q-tile, 8 waves + XCD-aware block swizzle ----------
#define KSP 40
#define PSP 140
#define VP  136
__global__ __launch_bounds__(512) void attn_self10_k(const u16* __restrict__ qb, const u16* __restrict__ kb,
                                                     const u16* __restrict__ vt,
                                                     u16* __restrict__ Opart, float* __restrict__ lpart) {
    __shared__ __align__(16) u16 Ks[128 * KSP];   // 10240 B
    __shared__ __align__(16) u16 Ps[128 * PSP];   // 35840 B
    __shared__ __align__(16) u16 Vs[48 * VP];     // 13056 B
    const int t = threadIdx.x;
    const int w = t >> 6, lane = t & 63, c = lane & 15, quad = lane >> 4;
    // XCD swizzle: dispatch id -> logical (q-tile, head, ks); bijective over 512 = 8*64
    const int did = blockIdx.x + 32 * (blockIdx.y + 8 * blockIdx.z);
    const int lid = (did & 7) * 64 + (did >> 3);
    const int hd = (lid >> 5) & 7, ks = lid >> 8;
    const int q0 = (lid & 31) * 128;
    const f4v zero = {0.f, 0.f, 0.f, 0.f};
    const s8v z8 = {0, 0, 0, 0, 0, 0, 0, 0};

    // zero pad V rows 41..47; row 40 = 1.0 (PV-ones: col 40 of O accumulates sum(P) = l)
    for (int i = t; i < 8 * VP / 2; i += 512) ((unsigned*)&Vs[40 * VP])[i] = 0u;
    __syncthreads();
    if (t < VP) Vs[40 * VP + t] = (u16)0x3F80;

    const u16* qrow = qb + (size_t)(q0 + w * 16 + c) * DMODEL + hd * DHEAD;
    s8v qa0 = *(const s8v*)(qrow + quad * 8);
    s8v qa1 = z8;
    if (quad == 0) qa1 = *(const s8v*)(qrow + 32);

    // ---- staging: K = 640 s8v slots (128 rows x 5 segs), V = 640 slots (40 rows x 16 segs)
    const int i0 = t, i2 = t + 512;
    const int r0 = i0 / 5, s0 = i0 - r0 * 5;
    const int r2 = (t < 128) ? i2 / 5 : r0, s2 = (t < 128) ? (i2 - (i2 / 5) * 5) : s0;
    const u16* kq0 = kb + (size_t)(ks * 2048 + r0) * DMODEL + hd * DHEAD + s0 * 8;
    const u16* kq2 = kb + (size_t)(ks * 2048 + r2) * DMODEL + hd * DHEAD + s2 * 8;
    u16* ksd0 = &Ks[r0 * KSP + s0 * 8];
    u16* ksd2 = &Ks[r2 * KSP + s2 * 8];
    const int d0 = i0 >> 4, g0v = i0 & 15;
    const int d2 = (t < 128) ? (i2 >> 4) : d0, g2v = (t < 128) ? (i2 & 15) : g0v;
    const u16* vq0 = vt + (size_t)(hd * DHEAD + d0) * N_SEQ + ks * 2048 + g0v * 8;
    const u16* vq2 = vt + (size_t)(hd * DHEAD + d2) * N_SEQ + ks * 2048 + g2v * 8;
    u16* vsd0 = &Vs[d0 * VP + g0v * 8];
    u16* vsd2 = &Vs[d2 * VP + g2v * 8];
    const size_t kadv = (size_t)128 * DMODEL;

    // prologue: load tile 0 into regs
    s8v kA = *(const s8v*)kq0, kC = *(const s8v*)kq2;
    s8v vA = *(const s8v*)vq0, vC = *(const s8v*)vq2;
    kq0 += kadv; kq2 += kadv;
    vq0 += 128;  vq2 += 128;

    f4v o0 = zero, o1 = zero, o2 = zero;

    for (int kt = 0; kt < 16; ++kt) {
        __syncthreads();                       // previous tile fully consumed (K by QK^T, V by PV)
        *(s8v*)ksd0 = kA; *(s8v*)vsd0 = vA;
        if (t < 128) { *(s8v*)ksd2 = kC; *(s8v*)vsd2 = vC; }
        if (kt + 1 < 16) {                     // issue next-tile loads; latency overlaps compute below
            kA = *(const s8v*)kq0; vA = *(const s8v*)vq0;
            if (t < 128) { kC = *(const s8v*)kq2; vC = *(const s8v*)vq2; }
            kq0 += kadv; kq2 += kadv;
            vq0 += 128;  vq2 += 128;
        }
        __syncthreads();                       // staged tile visible

        f4v sarr[8];
#pragma unroll
        for (int nt = 0; nt < 8; ++nt) {
            const int kr = nt * 16 + c;
            s8v b0 = *(const s8v*)&Ks[kr * KSP + quad * 8];
            s8v b1 = z8;
            if (quad == 0) b1 = *(const s8v*)&Ks[kr * KSP + 32];
            f4v s = __builtin_amdgcn_mfma_f32_16x16x32_bf16(qa0, b0, zero, 0, 0, 0);
            s = __builtin_amdgcn_mfma_f32_16x16x32_bf16(qa1, b1, s, 0, 0, 0);
            sarr[nt] = s;
        }

        u16* psw = &Ps[(size_t)(w * 16 + quad * 4) * PSP + c];
#pragma unroll
        for (int reg = 0; reg < 8; ++reg) {
            const int colb = (reg >> 2) * 64 + (reg & 3) * 16;
#pragma unroll
            for (int r = 0; r < 4; ++r) {
                float pv = exp2f(sarr[reg][r]);   // Q pre-scaled by scale*log2e
                psw[r * PSP + colb] = (u16)(__float_as_uint(pv) >> 16);   // truncate
            }
        }

        const u16* prow = &Ps[(size_t)(w * 16 + c) * PSP];
#pragma unroll
        for (int h2 = 0; h2 < 2; ++h2) {
            s8v pa0, pa1;
            {
                s4v lo = *(const s4v*)(prow + h2 * 64 + quad * 8);
                s4v hi = *(const s4v*)(prow + h2 * 64 + quad * 8 + 4);
                pa0 = (s8v){lo[0], lo[1], lo[2], lo[3], hi[0], hi[1], hi[2], hi[3]};
                s4v lo2 = *(const s4v*)(prow + h2 * 64 + 32 + quad * 8);
                s4v hi2 = *(const s4v*)(prow + h2 * 64 + 32 + quad * 8 + 4);
                pa1 = (s8v){lo2[0], lo2[1], lo2[2], lo2[3], hi2[0], hi2[1], hi2[2], hi2[3]};
            }
            {
                s8v v0 = *(const s8v*)&Vs[(0 * 16 + c) * VP + h2 * 64 + quad * 8];
                s8v v1 = *(const s8v*)&Vs[(0 * 16 + c) * VP + h2 * 64 + 32 + quad * 8];
                o0 = __builtin_amdgcn_mfma_f32_16x16x32_bf16(pa0, v0, o0, 0, 0, 0);
                o0 = __builtin_amdgcn_mfma_f32_16x16x32_bf16(pa1, v1, o0, 0, 0, 0);
            }
            {
                s8v v0 = *(const s8v*)&Vs[(1 * 16 + c) * VP + h2 * 64 + quad * 8];
                s8v v1 = *(const s8v*)&Vs[(1 * 16 + c) * VP + h2 * 64 + 32 + quad * 8];
                o1 = __builtin_amdgcn_mfma_f32_16x16x32_bf16(pa0, v0, o1, 0, 0, 0);
                o1 = __builtin_amdgcn_mfma_f32_16x16x32_bf16(pa1, v1, o1, 0, 0, 0);
            }
            {
                s8v v0 = *(const s8v*)&Vs[(2 * 16 + c) * VP + h2 * 64 + quad * 8];
                s8v v1 = *(const s8v*)&Vs[(2 * 16 + c) * VP + h2 * 64 + 32 + quad * 8];
                o2 = __builtin_amdgcn_mfma_f32_16x16x32_bf16(pa0, v0, o2, 0, 0, 0);
                o2 = __builtin_amdgcn_mfma_f32_16x16x32_bf16(pa1, v1, o2, 0, 0, 0);
            }
        }
    }

    const size_t pb = (size_t)(ks * 8 + hd) * N_SEQ;
#pragma unroll
    for (int r = 0; r < 4; ++r) {
        int q = q0 + w * 16 + quad * 4 + r;
        u16* op = Opart + (pb + q) * DHEAD;
        op[c]      = bf16u(o0[r]);
        op[16 + c] = bf16u(o1[r]);
        if (c < 8) op[32 + c] = bf16u(o2[r]);
        if (c == 8) lpart[pb + q] = o2[r];   // col 40 = sum(P) via ones-row
    }
}

// ---------------- Cross-attention v3: MFMA tile kernel, 77 keys padded to 80/96 ----------------
__global__ __launch_bounds__(256) void attn_cross3_k(const u16* __restrict__ qb,   // [4096][320] bf16
                                                     const u16* __restrict__ kb,   // [77][320]  bf16
                                                     const u16* __restrict__ vt,   // [320][128] bf16 (cols>=77 garbage)
                                                     u16* __restrict__ outb) {     // [4096][320] bf16
    __shared__ __align__(16) u16 KsPs[64 * PSP];
    __shared__ __align__(16) u16 Vs[48 * VP];
    const int t = threadIdx.x;
    const int w = t >> 6, lane = t & 63, c = lane & 15, quad = lane >> 4;
    const int hd = blockIdx.y;
    const int q0 = blockIdx.x * 64;
    const float SC2 = 0.15811388300841897f * 1.4426950408889634f;
    const f4v zero = {0.f, 0.f, 0.f, 0.f};
    const s8v z8 = {0, 0, 0, 0, 0, 0, 0, 0};

    for (int i = t; i < 48 * VP / 2; i += 256) ((unsigned*)Vs)[i] = 0u;
    __syncthreads();
    if (t < VP) Vs[40 * VP + t] = (u16)0x3F80;        // ones row -> col 40 of O = sum(P) = l
    for (int i = t; i < 400; i += 256) {              // V: 40 d-rows x 10 chunks of 8 keys
        int d = i / 10, kc = i - d * 10;
        s8v v = *(const s8v*)(vt + (size_t)(hd * DHEAD + d) * 128 + kc * 8);
        if (kc == 9) { v[5] = 0; v[6] = 0; v[7] = 0; } // keys 77..79 garbage -> 0
        *(s8v*)&Vs[d * VP + kc * 8] = v;
    }
    for (int i = t; i < 385; i += 256) {              // K rows 0..76 (77..79 left garbage, masked later)
        int r = i / 5, sg = i - r * 5;
        *(s8v*)&KsPs[r * KSP + sg * 8] = *(const s8v*)(kb + (size_t)r * DMODEL + hd * DHEAD + sg * 8);
    }
    const u16* qrow = qb + (size_t)(q0 + w * 16 + c) * DMODEL + hd * DHEAD;
    s8v qa0 = *(const s8v*)(qrow + quad * 8);
    s8v qa1 = z8;
    if (quad == 0) qa1 = *(const s8v*)(qrow + 32);
    __syncthreads();

    f4v sarr[5];
#pragma unroll
    for (int nt = 0; nt < 5; ++nt) {
        const int kr = nt * 16 + c;
        s8v b0 = *(const s8v*)&KsPs[kr * KSP + quad * 8];
        s8v b1 = z8;
        if (quad == 0) b1 = *(const s8v*)&KsPs[kr * KSP + 32];
        f4v s = __builtin_amdgcn_mfma_f32_16x16x32_bf16(qa0, b0, zero, 0, 0, 0);
        s = __builtin_amdgcn_mfma_f32_16x16x32_bf16(qa1, b1, s, 0, 0, 0);
        sarr[nt] = s;
    }
    __syncthreads();   // all waves done reading K; reuse buffer for P

    u16* psw = &KsPs[(size_t)(w * 16 + quad * 4) * PSP + c];
#pragma unroll
    for (int r = 0; r < 4; ++r) {
        float s4 = (c < 13) ? sarr[4][r] : -1e30f;    // mask cols 77..79 (garbage K rows)
        float mx = fmaxf(fmaxf(fmaxf(sarr[0][r], sarr[1][r]), fmaxf(sarr[2][r], sarr[3][r])), s4);
        mx = fmaxf(mx, __shfl_xor(mx, 1));
        mx = fmaxf(mx, __shfl_xor(mx, 2));
        mx = fmaxf(mx, __shfl_xor(mx, 4));
        mx = fmaxf(mx, __shfl_xor(mx, 8));
#pragma unroll
        for (int nt = 0; nt < 4; ++nt)
            psw[r * PSP + nt * 16] = bf16u(exp2f((sarr[nt][r] - mx) * SC2));
        psw[r * PSP + 64] = (c < 13) ? bf16u(exp2f((s4 - mx) * SC2)) : (u16)0;
        psw[r * PSP + 80] = 0;                        // cols 80..95
    }

    const u16* prow = &KsPs[(size_t)(w * 16 + c) * PSP];
    f4v o0 = zero, o1 = zero, o2 = zero;
#pragma unroll
    for (int ch = 0; ch < 3; ++ch) {
        s4v lo = *(const s4v*)(prow + ch * 32 + quad * 8);
        s4v hi = *(const s4v*)(prow + ch * 32 + quad * 8 + 4);
        s8v pa = (s8v){lo[0], lo[1], lo[2], lo[3], hi[0], hi[1], hi[2], hi[3]};
        s8v v0 = *(const s8v*)&Vs[(0 * 16 + c) * VP + ch * 32 + quad * 8];
        o0 = __builtin_amdgcn_mfma_f32_16x16x32_bf16(pa, v0, o0, 0, 0, 0);
        s8v v1 = *(const s8v*)&Vs[(1 * 16 + c) * VP + ch * 32 + quad * 8];
        o1 = __builtin_amdgcn_mfma_f32_16x16x32_bf16(pa, v1, o1, 0, 0, 0);
        s8v v2 = *(const s8v*)&Vs[(2 * 16 + c) * VP + ch * 32 + quad * 8];
        o2 = __builtin_amdgcn_mfma_f32_16x16x32_bf16(pa, v2, o2, 0, 0, 0);
    }

#pragma unroll
    for (int r = 0; r < 4; ++r) {
        float inv = 1.f / __shfl(o2[r], (lane & 48) | 8);   // l lives at col 40 -> o2 tile, c==8
        int q = q0 + w * 16 + quad * 4 + r;
        u16* op = outb + (size_t)q * DMODEL + hd * DHEAD;
        op[c]      = bf16u(o0[r] * inv);
        op[16 + c] = bf16u(o1[r] * inv);
        if (c < 8) op[32 + c] = bf16u(o2[r] * inv);
    }
}

extern "C" void kernel_launch(void* const* d_in, const int* in_sizes, int n_in,
                              void* d_out, int out_size, void* d_ws, size_t ws_size,
                              hipStream_t stream) {
    const float* x      = (const float*)d_in[0];
    const float* ctx    = (const float*)d_in[1];
    const float* gn_w   = (const float*)d_in[2];
    const float* gn_b   = (const float*)d_in[3];
    const float* pin_w  = (const float*)d_in[4];
    const float* pin_b  = (const float*)d_in[5];
    const float* ln1_w  = (const float*)d_in[6];
    const float* ln1_b  = (const float*)d_in[7];
    const float* q1     = (const float*)d_in[8];
    const float* k1     = (const float*)d_in[9];
    const float* v1     = (const float*)d_in[10];
    const float* o1_w   = (const float*)d_in[11];
    const float* o1_b   = (const float*)d_in[12];
    const float* ln2_w  = (const float*)d_in[13];
    const float* ln2_b  = (const float*)d_in[14];
    const float* q2     = (const float*)d_in[15];
    const float* k2     = (const float*)d_in[16];
    const float* v2     = (const float*)d_in[17];
    const float* o2_w   = (const float*)d_in[18];
    const float* o2_b   = (const float*)d_in[19];
    const float* ln3_w  = (const float*)d_in[20];
    const float* ln3_b  = (const float*)d_in[21];
    const float* ff1_w  = (const float*)d_in[22];
    const float* ff1_b  = (const float*)d_in[23];
    const float* ff2_w  = (const float*)d_in[24];
    const float* ff2_b  = (const float*)d_in[25];
    const float* pout_w = (const float*)d_in[26];
    const float* pout_b = (const float*)d_in[27];
    float* out = (float*)d_out;

    char* base = (char*)d_ws;
    float* h     = (float*)(base);
    u16*   qb16  = (u16*)(base + 5242880);
    u16*   kb16  = (u16*)(base + 7864320);
    u16*   vt16  = (u16*)(base + 10485760);
    u16*   ao16  = (u16*)(base + 13107200);
    u16*   ffg16 = (u16*)(base + 5242880);
    u16*   wbase = (u16*)(base + 15728640);
    u16* pinT  = wbase;
    u16* q1T   = pinT  + 102400;
    u16* k1T   = q1T   + 102400;
    u16* v1T   = k1T   + 102400;
    u16* o1T   = v1T   + 102400;
    u16* q2T   = o1T   + 102400;
    u16* o2T   = q2T   + 102400;
    u16* k2T   = o2T   + 102400;
    u16* v2T   = k2T   + 245760;
    u16* ff1T  = v2T   + 245760;
    u16* ff2T  = ff1T  + 819200;
    u16* poutT = ff2T  + 409600;
    float* lnmu = (float*)(base + 20807680);
    float* lnrs = lnmu + 4096;
    u16*   k2b16 = (u16*)(lnrs + 4096);            // [77][320] bf16 keys
    u16*   v2t16 = (u16*)(lnrs + 4096 + 25600);    // [320][128] bf16 values (transposed, padded)
    u16*   Opart = (u16*)(lnrs + 4096 + 51200);
    float* lpart = (float*)(Opart + (size_t)2 * 8 * 4096 * 40);
    float* gnsc  = lpart + 2 * 8 * 4096;
    float* gnsh  = gnsc + 320;
    float* gpart = gnsh + 320;                     // 256 x 2 floats (GN partials)
    float* lnst  = gpart + 512;                    // 3 x 4096 x 2 floats (fused LN stats)

    // zero fused LN-stat accumulators (one memset replaces 3 ln_stats launches)
    hipMemsetAsync(lnst, 0, 3 * 8192 * sizeof(float), stream);

    WCs wd;
    wd.a[0]  = {pin_w,  pinT,  320,  320,  0};
    wd.a[1]  = {q1,     q1T,   320,  320,  1};
    wd.a[2]  = {k1,     k1T,   320,  320,  1};
    wd.a[3]  = {v1,     v1T,   320,  320,  1};
    wd.a[4]  = {o1_w,   o1T,   320,  320,  1};
    wd.a[5]  = {q2,     q2T,   320,  320,  1};
    wd.a[6]  = {o2_w,   o2T,   320,  320,  1};
    wd.a[7]  = {k2,     k2T,   768,  320,  1};
    wd.a[8]  = {v2,     v2T,   768,  320,  1};
    wd.a[9]  = {ff1_w,  ff1T,  320,  2560, 1};
    wd.a[10] = {ff2_w,  ff2T,  1280, 320,  1};
    wd.a[11] = {pout_w, poutT, 320,  320,  0};
    wcast2_k<<<dim3(800, 12), 256, 0, stream>>>(wd);

    GArg gz = {nullptr, nullptr, nullptr, nullptr, 0};
    float* st1 = lnst;            // LN1 stats (h after proj_in)
    float* st2 = lnst + 8192;     // LN2 stats (h after o1)
    float* st3 = lnst + 16384;    // LN3 stats (h after o2)

    // 1. GN stats (2-stage); proj_in (GN fused in staging) -> h, fused LN1 stats
    gn_part_k<<<256, 256, 0, stream>>>(x, gpart);
    gn_fin_k<<<1, 320, 0, stream>>>(gpart, gn_w, gn_b, gnsc, gnsh);
    {
        GArg g0 = {pinT, pin_b, h, nullptr, 0};
        gemm_t<0><<<dim3(5, 64, 1), 256, 0, stream>>>(x, 2, 4096, nullptr, nullptr, gnsc, gnsh,
                                                      g0, gz, gz, nullptr, st1, 4096, 320, 320, 0);
    }
    // 2. qkv fused (LN1-from-stats in staging); Q written pre-scaled by scale*log2e
    {
        GArg g0 = {q1T, nullptr, nullptr, qb16, 4};
        GArg g1 = {nullptr, nullptr, nullptr, kb16, 0};
        GArg g2 = {nullptr, nullptr, nullptr, vt16, 0};
        gemm_t<1><<<dim3(15, 64, 1), 256, 0, stream>>>(h, 3, 320, st1, nullptr, ln1_w, ln1_b,
                                                       g0, g1, g2, nullptr, nullptr, 4096, 320, 960, 4096);
    }
    attn_self10_k<<<dim3(32, 8, 2), 512, 0, stream>>>(qb16, kb16, vt16, Opart, lpart);
    // 3. o1 proj: A = combined 2-split partials, residual h -> h, fused LN2 stats
    {
        GArg g0 = {o1T, o1_b, h, nullptr, 0};
        gemm_t<2><<<dim3(5, 64, 1), 256, 0, stream>>>(Opart, 4, 0, lpart, nullptr, nullptr, nullptr,
                                                      g0, gz, gz, h, st2, 4096, 320, 320, 0);
    }
    // 4. cross-attention block (LN2-from-stats in q2 staging)
    {
        GArg g0 = {q2T, nullptr, nullptr, qb16, 1};
        gemm_t<3><<<dim3(5, 64, 1), 256, 0, stream>>>(h, 3, 320, st2, nullptr, ln2_w, ln2_b,
                                                      g0, gz, gz, nullptr, nullptr, 4096, 320, 320, 0);
    }
    {
        // K -> bf16 rows [77][320]; V -> bf16 transposed [320][128]
        GArg g0 = {k2T, nullptr, nullptr, k2b16, 1};
        GArg g1 = {v2T, nullptr, nullptr, v2t16, 2};
        gemm_t<4><<<dim3(5, 2, 2), 256, 0, stream>>>(ctx, 1, 768, nullptr, nullptr, nullptr, nullptr,
                                                     g0, g1, gz, nullptr, nullptr, 77, 768, 320, 128);
    }
    attn_cross3_k<<<dim3(64, 8), 256, 0, stream>>>(qb16, k2b16, v2t16, ao16);
    {
        GArg g0 = {o2T, o2_b, h, nullptr, 0};
        gemm_t<5><<<dim3(5, 64, 1), 256, 0, stream>>>(ao16, 0, 320, nullptr, nullptr, nullptr, nullptr,
                                                      g0, gz, gz, h, st3, 4096, 320, 320, 0);
    }
    // 5. GEGLU FF (LN3-from-stats in ff1 staging)
    gemm_gg<<<dim3(20, 64, 1), 256, 0, stream>>>(h, 320, st3, nullptr, ln3_w, ln3_b,
                                                 ff1T, ff1_b, ffg16, 320, 1280, 1280);
    {
        GArg g0 = {ff2T, ff2_b, h, nullptr, 0};
        gemm_t<6><<<dim3(5, 64, 1), 256, 0, stream>>>(ffg16, 0, 1280, nullptr, nullptr, nullptr, nullptr,
                                                      g0, gz, gz, h, nullptr, 4096, 1280, 320, 0);
    }
    // 6. proj_out + input residual
    {
        GArg g0 = {poutT, pout_b, out, nullptr, 3};
        gemm_t<7><<<dim3(5, 64, 1), 256, 0, stream>>>(h, 1, 320, nullptr, nullptr, nullptr, nullptr,
                                                      g0, gz, gz, x, nullptr, 4096, 320, 320, 4096);
    }
}

// Round 13
// 385.241 us; speedup vs baseline: 1.2550x; 1.2550x over previous
//
#include <hip/hip_runtime.h>
#include <hip/hip_bf16.h>
#include <math.h>

#define N_SEQ  4096
#define DMODEL 320
#define NHEADS 8
#define DHEAD  40
#define CTXN   77
#define CTXD   768
#define FFI    1280

typedef short s8v __attribute__((ext_vector_type(8)));
typedef short s4v __attribute__((ext_vector_type(4)));
typedef float f4v __attribute__((ext_vector_type(4)));
typedef unsigned short u16;

static __device__ __forceinline__ u16 bf16u(float x) {           // RNE
    unsigned u = __float_as_uint(x);
    return (u16)((u + 0x7FFFu + ((u >> 16) & 1u)) >> 16);
}
static __device__ __forceinline__ float b2f(u16 v) { return __uint_as_float((unsigned)v << 16); }
static __device__ __forceinline__ unsigned pack2(float a, float b) {
    return (unsigned)bf16u(a) | ((unsigned)bf16u(b) << 16);
}

// async global->LDS, 16B per lane; LDS dest = wave-uniform base + lane*16 (linear)
#define GLD_LDS16(gp, lp) __builtin_amdgcn_global_load_lds( \
    (const __attribute__((address_space(1))) void*)(gp),    \
    (__attribute__((address_space(3))) void*)(lp), 16, 0, 0)

// ---------------- weight pre-convert v2: coalesced tiled transpose ----------------
struct WC { const float* s; u16* d; int K, O, trans; };
struct WCs { WC a[12]; };
__global__ __launch_bounds__(256) void wcast2_k(WCs P) {
    __shared__ float tile[32][33];
    WC w = P.a[blockIdx.y];
    if (w.trans) {
        int ntk = w.K >> 5, nto = w.O >> 5;
        int tid = blockIdx.x;
        if (tid >= ntk * nto) return;
        int tk = tid % ntk, to = tid / ntk;
        int lr = threadIdx.x >> 5, lc = threadIdx.x & 31;
#pragma unroll
        for (int p = 0; p < 4; ++p) {
            int k = tk * 32 + p * 8 + lr;
            tile[p * 8 + lr][lc] = w.s[(size_t)k * w.O + to * 32 + lc];
        }
        __syncthreads();
#pragma unroll
        for (int p = 0; p < 4; ++p) {
            int o = to * 32 + p * 8 + lr;
            w.d[(size_t)o * w.K + tk * 32 + lc] = bf16u(tile[lc][p * 8 + lr]);
        }
    } else {
        int nel = w.K * w.O;
        for (int e = blockIdx.x * 256 + threadIdx.x; e < nel; e += gridDim.x * 256)
            w.d[e] = bf16u(w.s[e]);
    }
}

// ---------------- GroupNorm stats v2: 2-stage reduction (256 blocks, float4 loads) ----------------
__global__ __launch_bounds__(256) void gn_part_k(const float* __restrict__ x, float* __restrict__ part) {
    __shared__ float red[128];
    const int b = blockIdx.x;
    const int g = b >> 3, ch = b & 7;
    const float4* xp = (const float4*)(x + (size_t)g * 40960) + ch * 1280;
    float s = 0.f, ss = 0.f;
#pragma unroll
    for (int i = 0; i < 5; ++i) {
        float4 v = xp[threadIdx.x + 256 * i];
        s  += v.x + v.y + v.z + v.w;
        ss += v.x * v.x + v.y * v.y + v.z * v.z + v.w * v.w;
    }
    for (int o = 32; o > 0; o >>= 1) { s += __shfl_xor(s, o); ss += __shfl_xor(ss, o); }
    const int w = threadIdx.x >> 6, l = threadIdx.x & 63;
    if (l == 0) { red[w] = s; red[64 + w] = ss; }
    __syncthreads();
    if (threadIdx.x == 0) {
        part[b * 2]     = red[0] + red[1] + red[2] + red[3];
        part[b * 2 + 1] = red[64] + red[65] + red[66] + red[67];
    }
}
__global__ __launch_bounds__(320) void gn_fin_k(const float* __restrict__ part,
                                                const float* __restrict__ gw, const float* __restrict__ gb,
                                                float* __restrict__ sc, float* __restrict__ sh) {
    __shared__ float ms[32][2];
    const int t = threadIdx.x;
    if (t < 32) {
        float s = 0.f, ss = 0.f;
#pragma unroll
        for (int ch = 0; ch < 8; ++ch) { s += part[(t * 8 + ch) * 2]; ss += part[(t * 8 + ch) * 2 + 1]; }
        float mean = s * (1.f / 40960.f);
        float var  = ss * (1.f / 40960.f) - mean * mean;
        ms[t][0] = mean; ms[t][1] = rsqrtf(var + 1e-6f);
    }
    __syncthreads();
    if (t < 320) {
        int g = t / 10;
        float scv = gw[t] * ms[g][1];
        sc[t] = scv;
        sh[t] = gb[t] - ms[g][0] * scv;
    }
}

// ---------------- LayerNorm stats ----------------
__global__ __launch_bounds__(256) void ln_stats_k(const float* __restrict__ in,
                                                  float* __restrict__ mu, float* __restrict__ rs) {
    int row = blockIdx.x * 4 + (threadIdx.x >> 6), l = threadIdx.x & 63;
    const float* p = in + (size_t)row * DMODEL;
    float s = 0.f, ss = 0.f;
#pragma unroll
    for (int j = 0; j < 5; ++j) { float v = p[l + 64 * j]; s += v; ss += v * v; }
    for (int o = 32; o > 0; o >>= 1) { s += __shfl_xor(s, o); ss += __shfl_xor(ss, o); }
    if (l == 0) {
        float mean = s * (1.f / 320.f);
        float var  = ss * (1.f / 320.f) - mean * mean;
        mu[row] = mean;
        rs[row] = rsqrtf(var + 1e-5f);
    }
}

struct GArg { const u16* Wt; const float* bias; float* outf; u16* outb; int ob_mode; };
#define GP 72
// attn scale * log2e, folded into Q at the qkv epilogue (self-attn exp2f takes S directly)
#define QSCALE 0.22811012f

// ---------------- gemm_t<SITE>: 64x64 tile, K-chunk 64, reg-prefetch A + async W (global_load_lds) ----
template<int SITE>
__global__ __launch_bounds__(256) void gemm_t(const void* __restrict__ Av, int a_mode, int lda,
                                              const float* __restrict__ mu, const float* __restrict__ rs,
                                              const float* __restrict__ cw, const float* __restrict__ cb,
                                              GArg g0, GArg g1, GArg g2,
                                              const float* __restrict__ res,
                                              int Mrows, int K, int Oout, int obT_stride) {
    __shared__ __align__(16) u16 As[2][64 * GP];
    __shared__ __align__(16) u16 Wsm[2][64 * 64];
    const int t = threadIdx.x;
    const int w = t >> 6, lane = t & 63, c = lane & 15, quad = lane >> 4;
    const int o0 = blockIdx.x * 64, n0 = blockIdx.y * 64;
    GArg g = (blockIdx.z == 0) ? g0 : ((blockIdx.z == 1) ? g1 : g2);
    const f4v zero = {0.f, 0.f, 0.f, 0.f};
    f4v acc[4] = {zero, zero, zero, zero};
    const s8v z8 = {0, 0, 0, 0, 0, 0, 0, 0};
    const int nk = K >> 6;

    float fA[16];
    s8v bA0 = z8, bA1 = z8;

    // W source pointers: lane covers row o0 + w*16 + kk*8 + (l>>3), swizzled col
    const u16* gW0 = g.Wt + (size_t)(o0 + w * 16 + (lane >> 3)) * K + ((lane & 7) ^ (lane >> 3)) * 8;
    const u16* gW1 = gW0 + (size_t)8 * K;
    const int wdst = w * 1024;                 // u16 offset of this wave's W region
    const int swb0 = 8 * (quad ^ (c & 7));     // B-frag col (swizzled), half 0
    const int swb1 = 8 * ((quad + 4) ^ (c & 7)); // half 1 (+32 logical)

    auto gllW = [&](int b) {
        GLD_LDS16(gW0, &Wsm[b][wdst]);
        GLD_LDS16(gW1, &Wsm[b][wdst + 512]);
        gW0 += 64; gW1 += 64;
    };
    auto loadA = [&](int k0) {
        if (a_mode == 0) {
            const u16* A = (const u16*)Av;
            int i0 = t, i1 = t + 256;
            int nA = n0 + (i0 >> 3), nB = n0 + (i1 >> 3);
            bA0 = (nA < Mrows) ? *(const s8v*)(A + (size_t)nA * lda + k0 + (i0 & 7) * 8) : z8;
            bA1 = (nB < Mrows) ? *(const s8v*)(A + (size_t)nB * lda + k0 + (i1 & 7) * 8) : z8;
        } else if (a_mode == 1) {
            const float* A = (const float*)Av;
            int r = t >> 2, s16 = (t & 3) * 16;
            int n = n0 + r;
            if (n < Mrows) {
                const float* src = A + (size_t)n * lda + k0 + s16;
#pragma unroll
                for (int i = 0; i < 16; ++i) fA[i] = src[i];
            } else {
#pragma unroll
                for (int i = 0; i < 16; ++i) fA[i] = 0.f;
            }
        } else if (a_mode == 2) {
            const float* A = (const float*)Av;
#pragma unroll
            for (int j = 0; j < 16; ++j) {
                int e = t + 256 * j; int nn = e & 63, kk = e >> 6;
                int n = n0 + nn, kgl = k0 + kk;
                fA[j] = (n < Mrows) ? A[(size_t)kgl * lda + n] * cw[kgl] + cb[kgl] : 0.f;
            }
        } else if (a_mode == 3) {
            const float* A = (const float*)Av;
            int r = t >> 2, s16 = (t & 3) * 16;
            int n = n0 + r;
            if (n < Mrows) {
                const float* src = A + (size_t)n * lda + k0 + s16;
                const float* cwp = cw + k0 + s16;
                const float* cbp = cb + k0 + s16;
                float m_ = mu[n], rr = rs[n];
#pragma unroll
                for (int i = 0; i < 16; ++i) fA[i] = (src[i] - m_) * rr * cwp[i] + cbp[i];
            } else {
#pragma unroll
                for (int i = 0; i < 16; ++i) fA[i] = 0.f;
            }
        } else {   // 4: 2-split attention combine
            const u16* Op = (const u16*)Av;
            const float* lp = mu;
            int r = t >> 2, s16 = (t & 3) * 16;
            int n = n0 + r;
            int ch0 = k0 + s16;
            int hdA = ch0 / 40;
            int hdB = (ch0 + 15) / 40;
            float invA = 1.f / (lp[(size_t)hdA * N_SEQ + n] + lp[(size_t)(8 + hdA) * N_SEQ + n]);
            float invB = (hdB == hdA) ? invA
                       : 1.f / (lp[(size_t)hdB * N_SEQ + n] + lp[(size_t)(8 + hdB) * N_SEQ + n]);
#pragma unroll
            for (int i = 0; i < 16; ++i) {
                int ch = ch0 + i;
                int hd = ch / 40;
                int d  = ch - hd * 40;
                float num = b2f(Op[((size_t)hd * N_SEQ + n) * DHEAD + d])
                          + b2f(Op[((size_t)(8 + hd) * N_SEQ + n) * DHEAD + d]);
                fA[i] = num * ((hd == hdA) ? invA : invB);
            }
        }
    };
    auto storeA = [&](int b) {
        if (a_mode == 0) {
            int i0 = t, i1 = t + 256;
            *(s8v*)&As[b][(i0 >> 3) * GP + (i0 & 7) * 8] = bA0;
            *(s8v*)&As[b][(i1 >> 3) * GP + (i1 & 7) * 8] = bA1;
        } else if (a_mode == 2) {
#pragma unroll
            for (int j = 0; j < 16; ++j) {
                int e = t + 256 * j; int nn = e & 63, kk = e >> 6;
                As[b][nn * GP + kk] = bf16u(fA[j]);
            }
        } else {
            int r = t >> 2, s16 = (t & 3) * 16;
            unsigned* dst = (unsigned*)&As[b][r * GP + s16];
#pragma unroll
            for (int i = 0; i < 8; ++i) dst[i] = pack2(fA[2 * i], fA[2 * i + 1]);
        }
    };

    // pipeline with double buffer: one barrier per chunk
    gllW(0); loadA(0);
    storeA(0);
    __syncthreads();
    for (int k = 0; k < nk; ++k) {
        const int cur = k & 1;
        if (k + 1 < nk) { gllW(1 - cur); loadA((k + 1) << 6); }
        s8v a0 = *(const s8v*)&As[cur][(w * 16 + c) * GP + quad * 8];
        s8v a1 = *(const s8v*)&As[cur][(w * 16 + c) * GP + 32 + quad * 8];
#pragma unroll
        for (int nt = 0; nt < 4; ++nt) {
            s8v b0 = *(const s8v*)&Wsm[cur][(nt * 16 + c) * 64 + swb0];
            s8v b1 = *(const s8v*)&Wsm[cur][(nt * 16 + c) * 64 + swb1];
            acc[nt] = __builtin_amdgcn_mfma_f32_16x16x32_bf16(a0, b0, acc[nt], 0, 0, 0);
            acc[nt] = __builtin_amdgcn_mfma_f32_16x16x32_bf16(a1, b1, acc[nt], 0, 0, 0);
        }
        if (k + 1 < nk) { storeA(1 - cur); }
        __syncthreads();
    }
    // ---------- epilogue ----------
#pragma unroll
    for (int nt = 0; nt < 4; ++nt) {
        int o = o0 + nt * 16 + c;
        float vv[4];
#pragma unroll
        for (int r = 0; r < 4; ++r) vv[r] = acc[nt][r] + (g.bias ? g.bias[o] : 0.f);
        if (g.ob_mode == 3) {
            int nb = n0 + w * 16 + quad * 4;
            const float4 x4 = *(const float4*)(res + (size_t)o * obT_stride + nb);
            float4 o4 = make_float4(vv[0] + x4.x, vv[1] + x4.y, vv[2] + x4.z, vv[3] + x4.w);
            *(float4*)(g.outf + (size_t)o * obT_stride + nb) = o4;
        } else if (g.ob_mode == 4) {
#pragma unroll
            for (int r = 0; r < 4; ++r) {
                int n = n0 + w * 16 + quad * 4 + r;
                float vvv = vv[r];
                if (o < 320) vvv *= QSCALE;          // fold attn scale*log2e into Q
                u16 bv = bf16u(vvv);
                if (o < 320)      g0.outb[(size_t)n * 320 + o] = bv;
                else if (o < 640) g1.outb[(size_t)n * 320 + (o - 320)] = bv;
                else              g2.outb[(size_t)(o - 640) * obT_stride + n] = bv;
            }
        } else {
#pragma unroll
            for (int r = 0; r < 4; ++r) {
                int n = n0 + w * 16 + quad * 4 + r;
                if (n >= Mrows) continue;
                float v = vv[r];
                if (res) v += res[(size_t)n * Oout + o];
                if (g.outf) g.outf[(size_t)n * Oout + o] = v;
                if (g.ob_mode == 1) g.outb[(size_t)n * Oout + o] = bf16u(v);
                else if (g.ob_mode == 2) g.outb[(size_t)o * obT_stride + n] = bf16u(v);
            }
        }
    }
}

// ---------------- gemm_gg: ff1 GEGLU (LN staging), register-prefetch pipeline (single buffer) ---------
__global__ __launch_bounds__(256) void gemm_gg(const float* __restrict__ A, int lda,
                                               const float* __restrict__ mu, const float* __restrict__ rs,
                                               const float* __restrict__ cw, const float* __restrict__ cb,
                                               const u16* __restrict__ Wt, const float* __restrict__ bias,
                                               u16* __restrict__ outb,
                                               int K, int Oout, int geglu_off) {
    __shared__ __align__(16) u16 As[64 * GP];
    __shared__ __align__(16) u16 Wsm[64 * GP];
    __shared__ __align__(16) u16 Wgm[64 * GP];
    const int t = threadIdx.x;
    const int w = t >> 6, lane = t & 63, c = lane & 15, quad = lane >> 4;
    const int o0 = blockIdx.x * 64, n0 = blockIdx.y * 64;
    const f4v zero = {0.f, 0.f, 0.f, 0.f};
    f4v acc[4]  = {zero, zero, zero, zero};
    f4v accg[4] = {zero, zero, zero, zero};
    const int nk = K >> 6;

    float fA[16];
    s8v wv0, wv1, gv0, gv1;

    auto loadWG = [&](int k0) {
        int i0 = t, i1 = t + 256;
        wv0 = *(const s8v*)(Wt + (size_t)(o0 + (i0 >> 3)) * K + k0 + (i0 & 7) * 8);
        wv1 = *(const s8v*)(Wt + (size_t)(o0 + (i1 >> 3)) * K + k0 + (i1 & 7) * 8);
        gv0 = *(const s8v*)(Wt + (size_t)(o0 + (i0 >> 3) + geglu_off) * K + k0 + (i0 & 7) * 8);
        gv1 = *(const s8v*)(Wt + (size_t)(o0 + (i1 >> 3) + geglu_off) * K + k0 + (i1 & 7) * 8);
    };
    auto storeWG = [&]() {
        int i0 = t, i1 = t + 256;
        *(s8v*)&Wsm[(i0 >> 3) * GP + (i0 & 7) * 8] = wv0;
        *(s8v*)&Wsm[(i1 >> 3) * GP + (i1 & 7) * 8] = wv1;
        *(s8v*)&Wgm[(i0 >> 3) * GP + (i0 & 7) * 8] = gv0;
        *(s8v*)&Wgm[(i1 >> 3) * GP + (i1 & 7) * 8] = gv1;
    };
    auto loadA = [&](int k0) {
        int r = t >> 2, s16 = (t & 3) * 16;
        int n = n0 + r;
        const float* src = A + (size_t)n * lda + k0 + s16;
        const float* cwp = cw + k0 + s16;
        const float* cbp = cb + k0 + s16;
        float m_ = mu[n], rr = rs[n];
#pragma unroll
        for (int i = 0; i < 16; ++i) fA[i] = (src[i] - m_) * rr * cwp[i] + cbp[i];
    };
    auto storeA = [&]() {
        int r = t >> 2, s16 = (t & 3) * 16;
        unsigned* dst = (unsigned*)&As[r * GP + s16];
#pragma unroll
        for (int i = 0; i < 8; ++i) dst[i] = pack2(fA[2 * i], fA[2 * i + 1]);
    };

    loadA(0); loadWG(0);
    storeA(); storeWG();
    __syncthreads();
    for (int k = 0; k < nk; ++k) {
        if (k + 1 < nk) { loadA((k + 1) << 6); loadWG((k + 1) << 6); }
        s8v a0 = *(const s8v*)&As[(w * 16 + c) * GP + quad * 8];
        s8v a1 = *(const s8v*)&As[(w * 16 + c) * GP + 32 + quad * 8];
#pragma unroll
        for (int nt = 0; nt < 4; ++nt) {
            s8v b0 = *(const s8v*)&Wsm[(nt * 16 + c) * GP + quad * 8];
            s8v b1 = *(const s8v*)&Wsm[(nt * 16 + c) * GP + 32 + quad * 8];
            acc[nt] = __builtin_amdgcn_mfma_f32_16x16x32_bf16(a0, b0, acc[nt], 0, 0, 0);
            acc[nt] = __builtin_amdgcn_mfma_f32_16x16x32_bf16(a1, b1, acc[nt], 0, 0, 0);
            s8v q0 = *(const s8v*)&Wgm[(nt * 16 + c) * GP + quad * 8];
            s8v q1 = *(const s8v*)&Wgm[(nt * 16 + c) * GP + 32 + quad * 8];
            accg[nt] = __builtin_amdgcn_mfma_f32_16x16x32_bf16(a0, q0, accg[nt], 0, 0, 0);
            accg[nt] = __builtin_amdgcn_mfma_f32_16x16x32_bf16(a1, q1, accg[nt], 0, 0, 0);
        }
        __syncthreads();
        if (k + 1 < nk) {
            storeA(); storeWG();
            __syncthreads();
        }
    }
#pragma unroll
    for (int nt = 0; nt < 4; ++nt) {
        int o = o0 + nt * 16 + c;
#pragma unroll
        for (int r = 0; r < 4; ++r) {
            int n = n0 + w * 16 + quad * 4 + r;
            float v = acc[nt][r] + bias[o];
            float gg = accg[nt][r] + bias[o + geglu_off];
            v = v * 0.5f * gg * (1.f + erff(gg * 0.70710678118654752f));
            outb[(size_t)n * Oout + o] = bf16u(v);
        }
    }
}

// ---------------- Self-attention v10b: 128-row Q-tile, 8 waves + XCD-aware block swizzle ----------
// lid = (did&7)*64 + did>>3 groups all 32 q-tiles of a (head,ks) pair onto one XCD
// (each XCD gets 2 complete groups = 656KB K+V, L2-resident) -> K/V fetched once per XCD.
#define KSP 40
#define PSP 140
#define VP  136
__global__ __launch_bounds__(512) void attn_self10_k(const u16* __restrict__ qb, const u16* __restrict__ kb,
                                                     const u16* __restrict__ vt,
                                                     u16* __restrict__ Opart, float* __restrict__ lpart) {
    __shared__ __align__(16) u16 Ks[128 * KSP];   // 10240 B
    __shared__ __align__(16) u16 Ps[128 * PSP];   // 35840 B
    __shared__ __align__(16) u16 Vs[48 * VP];     // 13056 B
    const int t = threadIdx.x;
    const int w = t >> 6, lane = t & 63, c = lane & 15, quad = lane >> 4;
    // XCD swizzle: dispatch id -> logical (q-tile, head, ks); bijective over 512 = 8*64
    const int did = blockIdx.x + 32 * (blockIdx.y + 8 * blockIdx.z);
    const int lid = (did & 7) * 64 + (did >> 3);
    const int hd = (lid >> 5) & 7, ks = lid >> 8;
    const int q0 = (lid & 31) * 128;
    const f4v zero = {0.f, 0.f, 0.f, 0.f};
    const s8v z8 = {0, 0, 0, 0, 0, 0, 0, 0};

    // zero pad V rows 41..47; row 40 = 1.0 (PV-ones: col 40 of O accumulates sum(P) = l)
    for (int i = t; i < 8 * VP / 2; i += 512) ((unsigned*)&Vs[40 * VP])[i] = 0u;
    __syncthreads();
    if (t < VP) Vs[40 * VP + t] = (u16)0x3F80;

    const u16* qrow = qb + (size_t)(q0 + w * 16 + c) * DMODEL + hd * DHEAD;
    s8v qa0 = *(const s8v*)(qrow + quad * 8);
    s8v qa1 = z8;
    if (quad == 0) qa1 = *(const s8v*)(qrow + 32);

    // ---- staging: K = 640 s8v slots (128 rows x 5 segs), V = 640 slots (40 rows x 16 segs)
    const int i0 = t, i2 = t + 512;
    const int r0 = i0 / 5, s0 = i0 - r0 * 5;
    const int r2 = (t < 128) ? i2 / 5 : r0, s2 = (t < 128) ? (i2 - (i2 / 5) * 5) : s0;
    const u16* kq0 = kb + (size_t)(ks * 2048 + r0) * DMODEL + hd * DHEAD + s0 * 8;
    const u16* kq2 = kb + (size_t)(ks * 2048 + r2) * DMODEL + hd * DHEAD + s2 * 8;
    u16* ksd0 = &Ks[r0 * KSP + s0 * 8];
    u16* ksd2 = &Ks[r2 * KSP + s2 * 8];
    const int d0 = i0 >> 4, g0v = i0 & 15;
    const int d2 = (t < 128) ? (i2 >> 4) : d0, g2v = (t < 128) ? (i2 & 15) : g0v;
    const u16* vq0 = vt + (size_t)(hd * DHEAD + d0) * N_SEQ + ks * 2048 + g0v * 8;
    const u16* vq2 = vt + (size_t)(hd * DHEAD + d2) * N_SEQ + ks * 2048 + g2v * 8;
    u16* vsd0 = &Vs[d0 * VP + g0v * 8];
    u16* vsd2 = &Vs[d2 * VP + g2v * 8];
    const size_t kadv = (size_t)128 * DMODEL;

    // prologue: load tile 0 into regs
    s8v kA = *(const s8v*)kq0, kC = *(const s8v*)kq2;
    s8v vA = *(const s8v*)vq0, vC = *(const s8v*)vq2;
    kq0 += kadv; kq2 += kadv;
    vq0 += 128;  vq2 += 128;

    f4v o0 = zero, o1 = zero, o2 = zero;

    for (int kt = 0; kt < 16; ++kt) {
        __syncthreads();                       // previous tile fully consumed (K by QK^T, V by PV)
        *(s8v*)ksd0 = kA; *(s8v*)vsd0 = vA;
        if (t < 128) { *(s8v*)ksd2 = kC; *(s8v*)vsd2 = vC; }
        if (kt + 1 < 16) {                     // issue next-tile loads; latency overlaps compute below
            kA = *(const s8v*)kq0; vA = *(const s8v*)vq0;
            if (t < 128) { kC = *(const s8v*)kq2; vC = *(const s8v*)vq2; }
            kq0 += kadv; kq2 += kadv;
            vq0 += 128;  vq2 += 128;
        }
        __syncthreads();                       // staged tile visible

        f4v sarr[8];
#pragma unroll
        for (int nt = 0; nt < 8; ++nt) {
            const int kr = nt * 16 + c;
            s8v b0 = *(const s8v*)&Ks[kr * KSP + quad * 8];
            s8v b1 = z8;
            if (quad == 0) b1 = *(const s8v*)&Ks[kr * KSP + 32];
            f4v s = __builtin_amdgcn_mfma_f32_16x16x32_bf16(qa0, b0, zero, 0, 0, 0);
            s = __builtin_amdgcn_mfma_f32_16x16x32_bf16(qa1, b1, s, 0, 0, 0);
            sarr[nt] = s;
        }

        u16* psw = &Ps[(size_t)(w * 16 + quad * 4) * PSP + c];
#pragma unroll
        for (int reg = 0; reg < 8; ++reg) {
            const int colb = (reg >> 2) * 64 + (reg & 3) * 16;
#pragma unroll
            for (int r = 0; r < 4; ++r) {
                float pv = exp2f(sarr[reg][r]);   // Q pre-scaled by scale*log2e
                psw[r * PSP + colb] = (u16)(__float_as_uint(pv) >> 16);   // truncate
            }
        }

        const u16* prow = &Ps[(size_t)(w * 16 + c) * PSP];
#pragma unroll
        for (int h2 = 0; h2 < 2; ++h2) {
            s8v pa0, pa1;
            {
                s4v lo = *(const s4v*)(prow + h2 * 64 + quad * 8);
                s4v hi = *(const s4v*)(prow + h2 * 64 + quad * 8 + 4);
                pa0 = (s8v){lo[0], lo[1], lo[2], lo[3], hi[0], hi[1], hi[2], hi[3]};
                s4v lo2 = *(const s4v*)(prow + h2 * 64 + 32 + quad * 8);
                s4v hi2 = *(const s4v*)(prow + h2 * 64 + 32 + quad * 8 + 4);
                pa1 = (s8v){lo2[0], lo2[1], lo2[2], lo2[3], hi2[0], hi2[1], hi2[2], hi2[3]};
            }
            {
                s8v v0 = *(const s8v*)&Vs[(0 * 16 + c) * VP + h2 * 64 + quad * 8];
                s8v v1 = *(const s8v*)&Vs[(0 * 16 + c) * VP + h2 * 64 + 32 + quad * 8];
                o0 = __builtin_amdgcn_mfma_f32_16x16x32_bf16(pa0, v0, o0, 0, 0, 0);
                o0 = __builtin_amdgcn_mfma_f32_16x16x32_bf16(pa1, v1, o0, 0, 0, 0);
            }
            {
                s8v v0 = *(const s8v*)&Vs[(1 * 16 + c) * VP + h2 * 64 + quad * 8];
                s8v v1 = *(const s8v*)&Vs[(1 * 16 + c) * VP + h2 * 64 + 32 + quad * 8];
                o1 = __builtin_amdgcn_mfma_f32_16x16x32_bf16(pa0, v0, o1, 0, 0, 0);
                o1 = __builtin_amdgcn_mfma_f32_16x16x32_bf16(pa1, v1, o1, 0, 0, 0);
            }
            {
                s8v v0 = *(const s8v*)&Vs[(2 * 16 + c) * VP + h2 * 64 + quad * 8];
                s8v v1 = *(const s8v*)&Vs[(2 * 16 + c) * VP + h2 * 64 + 32 + quad * 8];
                o2 = __builtin_amdgcn_mfma_f32_16x16x32_bf16(pa0, v0, o2, 0, 0, 0);
                o2 = __builtin_amdgcn_mfma_f32_16x16x32_bf16(pa1, v1, o2, 0, 0, 0);
            }
        }
    }

    const size_t pb = (size_t)(ks * 8 + hd) * N_SEQ;
#pragma unroll
    for (int r = 0; r < 4; ++r) {
        int q = q0 + w * 16 + quad * 4 + r;
        u16* op = Opart + (pb + q) * DHEAD;
        op[c]      = bf16u(o0[r]);
        op[16 + c] = bf16u(o1[r]);
        if (c < 8) op[32 + c] = bf16u(o2[r]);
        if (c == 8) lpart[pb + q] = o2[r];   // col 40 = sum(P) via ones-row
    }
}

// ---------------- Cross-attention v3: MFMA tile kernel, 77 keys padded to 80/96 ----------------
__global__ __launch_bounds__(256) void attn_cross3_k(const u16* __restrict__ qb,   // [4096][320] bf16
                                                     const u16* __restrict__ kb,   // [77][320]  bf16
                                                     const u16* __restrict__ vt,   // [320][128] bf16 (cols>=77 garbage)
                                                     u16* __restrict__ outb) {     // [4096][320] bf16
    __shared__ __align__(16) u16 KsPs[64 * PSP];
    __shared__ __align__(16) u16 Vs[48 * VP];
    const int t = threadIdx.x;
    const int w = t >> 6, lane = t & 63, c = lane & 15, quad = lane >> 4;
    const int hd = blockIdx.y;
    const int q0 = blockIdx.x * 64;
    const float SC2 = 0.15811388300841897f * 1.4426950408889634f;
    const f4v zero = {0.f, 0.f, 0.f, 0.f};
    const s8v z8 = {0, 0, 0, 0, 0, 0, 0, 0};

    for (int i = t; i < 48 * VP / 2; i += 256) ((unsigned*)Vs)[i] = 0u;
    __syncthreads();
    if (t < VP) Vs[40 * VP + t] = (u16)0x3F80;        // ones row -> col 40 of O = sum(P) = l
    for (int i = t; i < 400; i += 256) {              // V: 40 d-rows x 10 chunks of 8 keys
        int d = i / 10, kc = i - d * 10;
        s8v v = *(const s8v*)(vt + (size_t)(hd * DHEAD + d) * 128 + kc * 8);
        if (kc == 9) { v[5] = 0; v[6] = 0; v[7] = 0; } // keys 77..79 garbage -> 0
        *(s8v*)&Vs[d * VP + kc * 8] = v;
    }
    for (int i = t; i < 385; i += 256) {              // K rows 0..76 (77..79 left garbage, masked later)
        int r = i / 5, sg = i - r * 5;
        *(s8v*)&KsPs[r * KSP + sg * 8] = *(const s8v*)(kb + (size_t)r * DMODEL + hd * DHEAD + sg * 8);
    }
    const u16* qrow = qb + (size_t)(q0 + w * 16 + c) * DMODEL + hd * DHEAD;
    s8v qa0 = *(const s8v*)(qrow + quad * 8);
    s8v qa1 = z8;
    if (quad == 0) qa1 = *(const s8v*)(qrow + 32);
    __syncthreads();

    f4v sarr[5];
#pragma unroll
    for (int nt = 0; nt < 5; ++nt) {
        const int kr = nt * 16 + c;
        s8v b0 = *(const s8v*)&KsPs[kr * KSP + quad * 8];
        s8v b1 = z8;
        if (quad == 0) b1 = *(const s8v*)&KsPs[kr * KSP + 32];
        f4v s = __builtin_amdgcn_mfma_f32_16x16x32_bf16(qa0, b0, zero, 0, 0, 0);
        s = __builtin_amdgcn_mfma_f32_16x16x32_bf16(qa1, b1, s, 0, 0, 0);
        sarr[nt] = s;
    }
    __syncthreads();   // all waves done reading K; reuse buffer for P

    u16* psw = &KsPs[(size_t)(w * 16 + quad * 4) * PSP + c];
#pragma unroll
    for (int r = 0; r < 4; ++r) {
        float s4 = (c < 13) ? sarr[4][r] : -1e30f;    // mask cols 77..79 (garbage K rows)
        float mx = fmaxf(fmaxf(fmaxf(sarr[0][r], sarr[1][r]), fmaxf(sarr[2][r], sarr[3][r])), s4);
        mx = fmaxf(mx, __shfl_xor(mx, 1));
        mx = fmaxf(mx, __shfl_xor(mx, 2));
        mx = fmaxf(mx, __shfl_xor(mx, 4));
        mx = fmaxf(mx, __shfl_xor(mx, 8));
#pragma unroll
        for (int nt = 0; nt < 4; ++nt)
            psw[r * PSP + nt * 16] = bf16u(exp2f((sarr[nt][r] - mx) * SC2));
        psw[r * PSP + 64] = (c < 13) ? bf16u(exp2f((s4 - mx) * SC2)) : (u16)0;
        psw[r * PSP + 80] = 0;                        // cols 80..95
    }

    const u16* prow = &KsPs[(size_t)(w * 16 + c) * PSP];
    f4v o0 = zero, o1 = zero, o2 = zero;
#pragma unroll
    for (int ch = 0; ch < 3; ++ch) {
        s4v lo = *(const s4v*)(prow + ch * 32 + quad * 8);
        s4v hi = *(const s4v*)(prow + ch * 32 + quad * 8 + 4);
        s8v pa = (s8v){lo[0], lo[1], lo[2], lo[3], hi[0], hi[1], hi[2], hi[3]};
        s8v v0 = *(const s8v*)&Vs[(0 * 16 + c) * VP + ch * 32 + quad * 8];
        o0 = __builtin_amdgcn_mfma_f32_16x16x32_bf16(pa, v0, o0, 0, 0, 0);
        s8v v1 = *(const s8v*)&Vs[(1 * 16 + c) * VP + ch * 32 + quad * 8];
        o1 = __builtin_amdgcn_mfma_f32_16x16x32_bf16(pa, v1, o1, 0, 0, 0);
        s8v v2 = *(const s8v*)&Vs[(2 * 16 + c) * VP + ch * 32 + quad * 8];
        o2 = __builtin_amdgcn_mfma_f32_16x16x32_bf16(pa, v2, o2, 0, 0, 0);
    }

#pragma unroll
    for (int r = 0; r < 4; ++r) {
        float inv = 1.f / __shfl(o2[r], (lane & 48) | 8);   // l lives at col 40 -> o2 tile, c==8
        int q = q0 + w * 16 + quad * 4 + r;
        u16* op = outb + (size_t)q * DMODEL + hd * DHEAD;
        op[c]      = bf16u(o0[r] * inv);
        op[16 + c] = bf16u(o1[r] * inv);
        if (c < 8) op[32 + c] = bf16u(o2[r] * inv);
    }
}

extern "C" void kernel_launch(void* const* d_in, const int* in_sizes, int n_in,
                              void* d_out, int out_size, void* d_ws, size_t ws_size,
                              hipStream_t stream) {
    const float* x      = (const float*)d_in[0];
    const float* ctx    = (const float*)d_in[1];
    const float* gn_w   = (const float*)d_in[2];
    const float* gn_b   = (const float*)d_in[3];
    const float* pin_w  = (const float*)d_in[4];
    const float* pin_b  = (const float*)d_in[5];
    const float* ln1_w  = (const float*)d_in[6];
    const float* ln1_b  = (const float*)d_in[7];
    const float* q1     = (const float*)d_in[8];
    const float* k1     = (const float*)d_in[9];
    const float* v1     = (const float*)d_in[10];
    const float* o1_w   = (const float*)d_in[11];
    const float* o1_b   = (const float*)d_in[12];
    const float* ln2_w  = (const float*)d_in[13];
    const float* ln2_b  = (const float*)d_in[14];
    const float* q2     = (const float*)d_in[15];
    const float* k2     = (const float*)d_in[16];
    const float* v2     = (const float*)d_in[17];
    const float* o2_w   = (const float*)d_in[18];
    const float* o2_b   = (const float*)d_in[19];
    const float* ln3_w  = (const float*)d_in[20];
    const float* ln3_b  = (const float*)d_in[21];
    const float* ff1_w  = (const float*)d_in[22];
    const float* ff1_b  = (const float*)d_in[23];
    const float* ff2_w  = (const float*)d_in[24];
    const float* ff2_b  = (const float*)d_in[25];
    const float* pout_w = (const float*)d_in[26];
    const float* pout_b = (const float*)d_in[27];
    float* out = (float*)d_out;

    char* base = (char*)d_ws;
    float* h     = (float*)(base);
    u16*   qb16  = (u16*)(base + 5242880);
    u16*   kb16  = (u16*)(base + 7864320);
    u16*   vt16  = (u16*)(base + 10485760);
    u16*   ao16  = (u16*)(base + 13107200);
    u16*   ffg16 = (u16*)(base + 5242880);
    u16*   wbase = (u16*)(base + 15728640);
    u16* pinT  = wbase;
    u16* q1T   = pinT  + 102400;
    u16* k1T   = q1T   + 102400;
    u16* v1T   = k1T   + 102400;
    u16* o1T   = v1T   + 102400;
    u16* q2T   = o1T   + 102400;
    u16* o2T   = q2T   + 102400;
    u16* k2T   = o2T   + 102400;
    u16* v2T   = k2T   + 245760;
    u16* ff1T  = v2T   + 245760;
    u16* ff2T  = ff1T  + 819200;
    u16* poutT = ff2T  + 409600;
    float* lnmu = (float*)(base + 20807680);
    float* lnrs = lnmu + 4096;
    u16*   k2b16 = (u16*)(lnrs + 4096);            // [77][320] bf16 keys
    u16*   v2t16 = (u16*)(lnrs + 4096 + 25600);    // [320][128] bf16 values (transposed, padded)
    u16*   Opart = (u16*)(lnrs + 4096 + 51200);
    float* lpart = (float*)(Opart + (size_t)2 * 8 * 4096 * 40);
    float* gnsc  = lpart + 2 * 8 * 4096;
    float* gnsh  = gnsc + 320;
    float* gpart = gnsh + 320;                     // 256 x 2 floats (GN partials)

    WCs wd;
    wd.a[0]  = {pin_w,  pinT,  320,  320,  0};
    wd.a[1]  = {q1,     q1T,   320,  320,  1};
    wd.a[2]  = {k1,     k1T,   320,  320,  1};
    wd.a[3]  = {v1,     v1T,   320,  320,  1};
    wd.a[4]  = {o1_w,   o1T,   320,  320,  1};
    wd.a[5]  = {q2,     q2T,   320,  320,  1};
    wd.a[6]  = {o2_w,   o2T,   320,  320,  1};
    wd.a[7]  = {k2,     k2T,   768,  320,  1};
    wd.a[8]  = {v2,     v2T,   768,  320,  1};
    wd.a[9]  = {ff1_w,  ff1T,  320,  2560, 1};
    wd.a[10] = {ff2_w,  ff2T,  1280, 320,  1};
    wd.a[11] = {pout_w, poutT, 320,  320,  0};
    wcast2_k<<<dim3(800, 12), 256, 0, stream>>>(wd);

    GArg gz = {nullptr, nullptr, nullptr, nullptr, 0};

    // 1. GN stats (2-stage, 256 blocks); proj_in (GN fused in staging)
    gn_part_k<<<256, 256, 0, stream>>>(x, gpart);
    gn_fin_k<<<1, 320, 0, stream>>>(gpart, gn_w, gn_b, gnsc, gnsh);
    {
        GArg g0 = {pinT, pin_b, h, nullptr, 0};
        gemm_t<0><<<dim3(5, 64, 1), 256, 0, stream>>>(x, 2, 4096, nullptr, nullptr, gnsc, gnsh,
                                                      g0, gz, gz, nullptr, 4096, 320, 320, 0);
    }
    // 2. qkv fused (LN1 in staging); Q written pre-scaled by scale*log2e
    ln_stats_k<<<1024, 256, 0, stream>>>(h, lnmu, lnrs);
    {
        GArg g0 = {q1T, nullptr, nullptr, qb16, 4};
        GArg g1 = {nullptr, nullptr, nullptr, kb16, 0};
        GArg g2 = {nullptr, nullptr, nullptr, vt16, 0};
        gemm_t<1><<<dim3(15, 64, 1), 256, 0, stream>>>(h, 3, 320, lnmu, lnrs, ln1_w, ln1_b,
                                                       g0, g1, g2, nullptr, 4096, 320, 960, 4096);
    }
    attn_self10_k<<<dim3(32, 8, 2), 512, 0, stream>>>(qb16, kb16, vt16, Opart, lpart);
    // 3. o1 proj: A = combined 2-split partials, residual h
    {
        GArg g0 = {o1T, o1_b, h, nullptr, 0};
        gemm_t<2><<<dim3(5, 64, 1), 256, 0, stream>>>(Opart, 4, 0, lpart, nullptr, nullptr, nullptr,
                                                      g0, gz, gz, h, 4096, 320, 320, 0);
    }
    // 4. cross-attention block (LN2 in q2 staging)
    ln_stats_k<<<1024, 256, 0, stream>>>(h, lnmu, lnrs);
    {
        GArg g0 = {q2T, nullptr, nullptr, qb16, 1};
        gemm_t<3><<<dim3(5, 64, 1), 256, 0, stream>>>(h, 3, 320, lnmu, lnrs, ln2_w, ln2_b,
                                                      g0, gz, gz, nullptr, 4096, 320, 320, 0);
    }
    {
        // K -> bf16 rows [77][320]; V -> bf16 transposed [320][128]
        GArg g0 = {k2T, nullptr, nullptr, k2b16, 1};
        GArg g1 = {v2T, nullptr, nullptr, v2t16, 2};
        gemm_t<4><<<dim3(5, 2, 2), 256, 0, stream>>>(ctx, 1, 768, nullptr, nullptr, nullptr, nullptr,
                                                     g0, g1, gz, nullptr, 77, 768, 320, 128);
    }
    attn_cross3_k<<<dim3(64, 8), 256, 0, stream>>>(qb16, k2b16, v2t16, ao16);
    {
        GArg g0 = {o2T, o2_b, h, nullptr, 0};
        gemm_t<5><<<dim3(5, 64, 1), 256, 0, stream>>>(ao16, 0, 320, nullptr, nullptr, nullptr, nullptr,
                                                      g0, gz, gz, h, 4096, 320, 320, 0);
    }
    // 5. GEGLU FF (LN3 in ff1 staging)
    ln_stats_k<<<1024, 256, 0, stream>>>(h, lnmu, lnrs);
    gemm_gg<<<dim3(20, 64, 1), 256, 0, stream>>>(h, 320, lnmu, lnrs, ln3_w, ln3_b,
                                                 ff1T, ff1_b, ffg16, 320, 1280, 1280);
    {
        GArg g0 = {ff2T, ff2_b, h, nullptr, 0};
        gemm_t<6><<<dim3(5, 64, 1), 256, 0, stream>>>(ffg16, 0, 1280, nullptr, nullptr, nullptr, nullptr,
                                                      g0, gz, gz, h, 4096, 1280, 320, 0);
    }
    // 6. proj_out + input residual
    {
        GArg g0 = {poutT, pout_b, out, nullptr, 3};
        gemm_t<7><<<dim3(5, 64, 1), 256, 0, stream>>>(h, 1, 320, nullptr, nullptr, nullptr, nullptr,
                                                      g0, gz, gz, x, 4096, 320, 320, 4096);
    }
}

// Round 14
// 372.568 us; speedup vs baseline: 1.2977x; 1.0340x over previous
//
#include <hip/hip_runtime.h>
#include <hip/hip_bf16.h>
#include <math.h>

#define N_SEQ  4096
#define DMODEL 320
#define NHEADS 8
#define DHEAD  40
#define CTXN   77
#define CTXD   768
#define FFI    1280

typedef short s8v __attribute__((ext_vector_type(8)));
typedef short s4v __attribute__((ext_vector_type(4)));
typedef float f4v __attribute__((ext_vector_type(4)));
typedef unsigned short u16;

static __device__ __forceinline__ u16 bf16u(float x) {           // RNE
    unsigned u = __float_as_uint(x);
    return (u16)((u + 0x7FFFu + ((u >> 16) & 1u)) >> 16);
}
static __device__ __forceinline__ float b2f(u16 v) { return __uint_as_float((unsigned)v << 16); }
static __device__ __forceinline__ unsigned pack2(float a, float b) {
    return (unsigned)bf16u(a) | ((unsigned)bf16u(b) << 16);
}

// async global->LDS, 16B per lane; LDS dest = wave-uniform base + lane*16 (linear)
#define GLD_LDS16(gp, lp) __builtin_amdgcn_global_load_lds( \
    (const __attribute__((address_space(1))) void*)(gp),    \
    (__attribute__((address_space(3))) void*)(lp), 16, 0, 0)

// ---------------- weight pre-convert v2: coalesced tiled transpose ----------------
struct WC { const float* s; u16* d; int K, O, trans; };
struct WCs { WC a[12]; };
__global__ __launch_bounds__(256) void wcast2_k(WCs P) {
    __shared__ float tile[32][33];
    WC w = P.a[blockIdx.y];
    if (w.trans) {
        int ntk = w.K >> 5, nto = w.O >> 5;
        int tid = blockIdx.x;
        if (tid >= ntk * nto) return;
        int tk = tid % ntk, to = tid / ntk;
        int lr = threadIdx.x >> 5, lc = threadIdx.x & 31;
#pragma unroll
        for (int p = 0; p < 4; ++p) {
            int k = tk * 32 + p * 8 + lr;
            tile[p * 8 + lr][lc] = w.s[(size_t)k * w.O + to * 32 + lc];
        }
        __syncthreads();
#pragma unroll
        for (int p = 0; p < 4; ++p) {
            int o = to * 32 + p * 8 + lr;
            w.d[(size_t)o * w.K + tk * 32 + lc] = bf16u(tile[lc][p * 8 + lr]);
        }
    } else {
        int nel = w.K * w.O;
        for (int e = blockIdx.x * 256 + threadIdx.x; e < nel; e += gridDim.x * 256)
            w.d[e] = bf16u(w.s[e]);
    }
}

// ---------------- GroupNorm stats v2: 2-stage reduction (256 blocks, float4 loads) ----------------
__global__ __launch_bounds__(256) void gn_part_k(const float* __restrict__ x, float* __restrict__ part) {
    __shared__ float red[128];
    const int b = blockIdx.x;
    const int g = b >> 3, ch = b & 7;
    const float4* xp = (const float4*)(x + (size_t)g * 40960) + ch * 1280;
    float s = 0.f, ss = 0.f;
#pragma unroll
    for (int i = 0; i < 5; ++i) {
        float4 v = xp[threadIdx.x + 256 * i];
        s  += v.x + v.y + v.z + v.w;
        ss += v.x * v.x + v.y * v.y + v.z * v.z + v.w * v.w;
    }
    for (int o = 32; o > 0; o >>= 1) { s += __shfl_xor(s, o); ss += __shfl_xor(ss, o); }
    const int w = threadIdx.x >> 6, l = threadIdx.x & 63;
    if (l == 0) { red[w] = s; red[64 + w] = ss; }
    __syncthreads();
    if (threadIdx.x == 0) {
        part[b * 2]     = red[0] + red[1] + red[2] + red[3];
        part[b * 2 + 1] = red[64] + red[65] + red[66] + red[67];
    }
}
__global__ __launch_bounds__(320) void gn_fin_k(const float* __restrict__ part,
                                                const float* __restrict__ gw, const float* __restrict__ gb,
                                                float* __restrict__ sc, float* __restrict__ sh) {
    __shared__ float ms[32][2];
    const int t = threadIdx.x;
    if (t < 32) {
        float s = 0.f, ss = 0.f;
#pragma unroll
        for (int ch = 0; ch < 8; ++ch) { s += part[(t * 8 + ch) * 2]; ss += part[(t * 8 + ch) * 2 + 1]; }
        float mean = s * (1.f / 40960.f);
        float var  = ss * (1.f / 40960.f) - mean * mean;
        ms[t][0] = mean; ms[t][1] = rsqrtf(var + 1e-6f);
    }
    __syncthreads();
    if (t < 320) {
        int g = t / 10;
        float scv = gw[t] * ms[g][1];
        sc[t] = scv;
        sh[t] = gb[t] - ms[g][0] * scv;
    }
}

// ---------------- LayerNorm stats ----------------
__global__ __launch_bounds__(256) void ln_stats_k(const float* __restrict__ in,
                                                  float* __restrict__ mu, float* __restrict__ rs) {
    int row = blockIdx.x * 4 + (threadIdx.x >> 6), l = threadIdx.x & 63;
    const float* p = in + (size_t)row * DMODEL;
    float s = 0.f, ss = 0.f;
#pragma unroll
    for (int j = 0; j < 5; ++j) { float v = p[l + 64 * j]; s += v; ss += v * v; }
    for (int o = 32; o > 0; o >>= 1) { s += __shfl_xor(s, o); ss += __shfl_xor(ss, o); }
    if (l == 0) {
        float mean = s * (1.f / 320.f);
        float var  = ss * (1.f / 320.f) - mean * mean;
        mu[row] = mean;
        rs[row] = rsqrtf(var + 1e-5f);
    }
}

struct GArg { const u16* Wt; const float* bias; float* outf; u16* outb; int ob_mode; };
#define GP 72
// attn scale * log2e, folded into Q at the qkv epilogue (self-attn exp2f takes S directly)
#define QSCALE 0.22811012f

// ---------------- gemm_t<SITE>: 64x64 tile, K-chunk 64, reg-prefetch A + async W (global_load_lds) ----
// SITE 3: merged launch — z=0 runs the q2 projection (a_mode 3); z=1/2 run the independent
// ctx K/V prep gemm (A=ctx passed via res, K=768, Mrows=77; blocks y>=2 exit immediately).
template<int SITE>
__global__ __launch_bounds__(256) void gemm_t(const void* __restrict__ Av, int a_mode, int lda,
                                              const float* __restrict__ mu, const float* __restrict__ rs,
                                              const float* __restrict__ cw, const float* __restrict__ cb,
                                              GArg g0, GArg g1, GArg g2,
                                              const float* __restrict__ res,
                                              int Mrows, int K, int Oout, int obT_stride) {
    __shared__ __align__(16) u16 As[2][64 * GP];
    __shared__ __align__(16) u16 Wsm[2][64 * 64];
    const int t = threadIdx.x;
    const int w = t >> 6, lane = t & 63, c = lane & 15, quad = lane >> 4;
    const int o0 = blockIdx.x * 64, n0 = blockIdx.y * 64;
    GArg g = (blockIdx.z == 0) ? g0 : ((blockIdx.z == 1) ? g1 : g2);
    const f4v zero = {0.f, 0.f, 0.f, 0.f};
    f4v acc[4] = {zero, zero, zero, zero};
    const s8v z8 = {0, 0, 0, 0, 0, 0, 0, 0};

    // per-z parameter overrides (SITE 3 merge); identity for all other sites
    int am = a_mode, ld = lda, Kk = K, Mr = Mrows, obs = obT_stride;
    const void* Ap = Av;
    const float* resp = res;
    if (SITE == 3) {
        resp = nullptr;                       // q2 never uses residual; res carries ctx pointer
        if (blockIdx.z > 0) {
            if (n0 >= 128) return;            // ctx has 77 rows -> only y<2 work
            am = 1; Ap = res; ld = CTXD; Kk = CTXD; Mr = CTXN; obs = 128;
        }
    }
    const int nk = Kk >> 6;

    float fA[16];
    s8v bA0 = z8, bA1 = z8;

    // W source pointers: lane covers row o0 + w*16 + kk*8 + (l>>3), swizzled col
    const u16* gW0 = g.Wt + (size_t)(o0 + w * 16 + (lane >> 3)) * Kk + ((lane & 7) ^ (lane >> 3)) * 8;
    const u16* gW1 = gW0 + (size_t)8 * Kk;
    const int wdst = w * 1024;                 // u16 offset of this wave's W region
    const int swb0 = 8 * (quad ^ (c & 7));     // B-frag col (swizzled), half 0
    const int swb1 = 8 * ((quad + 4) ^ (c & 7)); // half 1 (+32 logical)

    auto gllW = [&](int b) {
        GLD_LDS16(gW0, &Wsm[b][wdst]);
        GLD_LDS16(gW1, &Wsm[b][wdst + 512]);
        gW0 += 64; gW1 += 64;
    };
    auto loadA = [&](int k0) {
        if (am == 0) {
            const u16* A = (const u16*)Ap;
            int i0 = t, i1 = t + 256;
            int nA = n0 + (i0 >> 3), nB = n0 + (i1 >> 3);
            bA0 = (nA < Mr) ? *(const s8v*)(A + (size_t)nA * ld + k0 + (i0 & 7) * 8) : z8;
            bA1 = (nB < Mr) ? *(const s8v*)(A + (size_t)nB * ld + k0 + (i1 & 7) * 8) : z8;
        } else if (am == 1) {
            const float* A = (const float*)Ap;
            int r = t >> 2, s16 = (t & 3) * 16;
            int n = n0 + r;
            if (n < Mr) {
                const float* src = A + (size_t)n * ld + k0 + s16;
#pragma unroll
                for (int i = 0; i < 16; ++i) fA[i] = src[i];
            } else {
#pragma unroll
                for (int i = 0; i < 16; ++i) fA[i] = 0.f;
            }
        } else if (am == 2) {
            const float* A = (const float*)Ap;
#pragma unroll
            for (int j = 0; j < 16; ++j) {
                int e = t + 256 * j; int nn = e & 63, kk = e >> 6;
                int n = n0 + nn, kgl = k0 + kk;
                fA[j] = (n < Mr) ? A[(size_t)kgl * ld + n] * cw[kgl] + cb[kgl] : 0.f;
            }
        } else if (am == 3) {
            const float* A = (const float*)Ap;
            int r = t >> 2, s16 = (t & 3) * 16;
            int n = n0 + r;
            if (n < Mr) {
                const float* src = A + (size_t)n * ld + k0 + s16;
                const float* cwp = cw + k0 + s16;
                const float* cbp = cb + k0 + s16;
                float m_ = mu[n], rr = rs[n];
#pragma unroll
                for (int i = 0; i < 16; ++i) fA[i] = (src[i] - m_) * rr * cwp[i] + cbp[i];
            } else {
#pragma unroll
                for (int i = 0; i < 16; ++i) fA[i] = 0.f;
            }
        } else {   // 4: 2-split attention combine
            const u16* Op = (const u16*)Ap;
            const float* lp = mu;
            int r = t >> 2, s16 = (t & 3) * 16;
            int n = n0 + r;
            int ch0 = k0 + s16;
            int hdA = ch0 / 40;
            int hdB = (ch0 + 15) / 40;
            float invA = 1.f / (lp[(size_t)hdA * N_SEQ + n] + lp[(size_t)(8 + hdA) * N_SEQ + n]);
            float invB = (hdB == hdA) ? invA
                       : 1.f / (lp[(size_t)hdB * N_SEQ + n] + lp[(size_t)(8 + hdB) * N_SEQ + n]);
#pragma unroll
            for (int i = 0; i < 16; ++i) {
                int ch = ch0 + i;
                int hd = ch / 40;
                int d  = ch - hd * 40;
                float num = b2f(Op[((size_t)hd * N_SEQ + n) * DHEAD + d])
                          + b2f(Op[((size_t)(8 + hd) * N_SEQ + n) * DHEAD + d]);
                fA[i] = num * ((hd == hdA) ? invA : invB);
            }
        }
    };
    auto storeA = [&](int b) {
        if (am == 0) {
            int i0 = t, i1 = t + 256;
            *(s8v*)&As[b][(i0 >> 3) * GP + (i0 & 7) * 8] = bA0;
            *(s8v*)&As[b][(i1 >> 3) * GP + (i1 & 7) * 8] = bA1;
        } else if (am == 2) {
#pragma unroll
            for (int j = 0; j < 16; ++j) {
                int e = t + 256 * j; int nn = e & 63, kk = e >> 6;
                As[b][nn * GP + kk] = bf16u(fA[j]);
            }
        } else {
            int r = t >> 2, s16 = (t & 3) * 16;
            unsigned* dst = (unsigned*)&As[b][r * GP + s16];
#pragma unroll
            for (int i = 0; i < 8; ++i) dst[i] = pack2(fA[2 * i], fA[2 * i + 1]);
        }
    };

    // pipeline with double buffer: one barrier per chunk
    gllW(0); loadA(0);
    storeA(0);
    __syncthreads();
    for (int k = 0; k < nk; ++k) {
        const int cur = k & 1;
        if (k + 1 < nk) { gllW(1 - cur); loadA((k + 1) << 6); }
        s8v a0 = *(const s8v*)&As[cur][(w * 16 + c) * GP + quad * 8];
        s8v a1 = *(const s8v*)&As[cur][(w * 16 + c) * GP + 32 + quad * 8];
#pragma unroll
        for (int nt = 0; nt < 4; ++nt) {
            s8v b0 = *(const s8v*)&Wsm[cur][(nt * 16 + c) * 64 + swb0];
            s8v b1 = *(const s8v*)&Wsm[cur][(nt * 16 + c) * 64 + swb1];
            acc[nt] = __builtin_amdgcn_mfma_f32_16x16x32_bf16(a0, b0, acc[nt], 0, 0, 0);
            acc[nt] = __builtin_amdgcn_mfma_f32_16x16x32_bf16(a1, b1, acc[nt], 0, 0, 0);
        }
        if (k + 1 < nk) { storeA(1 - cur); }
        __syncthreads();
    }
    // ---------- epilogue ----------
#pragma unroll
    for (int nt = 0; nt < 4; ++nt) {
        int o = o0 + nt * 16 + c;
        float vv[4];
#pragma unroll
        for (int r = 0; r < 4; ++r) vv[r] = acc[nt][r] + (g.bias ? g.bias[o] : 0.f);
        if (g.ob_mode == 3) {
            int nb = n0 + w * 16 + quad * 4;
            const float4 x4 = *(const float4*)(resp + (size_t)o * obs + nb);
            float4 o4 = make_float4(vv[0] + x4.x, vv[1] + x4.y, vv[2] + x4.z, vv[3] + x4.w);
            *(float4*)(g.outf + (size_t)o * obs + nb) = o4;
        } else if (g.ob_mode == 4) {
#pragma unroll
            for (int r = 0; r < 4; ++r) {
                int n = n0 + w * 16 + quad * 4 + r;
                float vvv = vv[r];
                if (o < 320) vvv *= QSCALE;          // fold attn scale*log2e into Q
                u16 bv = bf16u(vvv);
                if (o < 320)      g0.outb[(size_t)n * 320 + o] = bv;
                else if (o < 640) g1.outb[(size_t)n * 320 + (o - 320)] = bv;
                else              g2.outb[(size_t)(o - 640) * obs + n] = bv;
            }
        } else {
#pragma unroll
            for (int r = 0; r < 4; ++r) {
                int n = n0 + w * 16 + quad * 4 + r;
                if (n >= Mr) continue;
                float v = vv[r];
                if (resp) v += resp[(size_t)n * Oout + o];
                if (g.outf) g.outf[(size_t)n * Oout + o] = v;
                if (g.ob_mode == 1) g.outb[(size_t)n * Oout + o] = bf16u(v);
                else if (g.ob_mode == 2) g.outb[(size_t)o * obs + n] = bf16u(v);
            }
        }
    }
}

// ---------------- gemm_gg: ff1 GEGLU (LN staging), register-prefetch pipeline (single buffer) ---------
__global__ __launch_bounds__(256) void gemm_gg(const float* __restrict__ A, int lda,
                                               const float* __restrict__ mu, const float* __restrict__ rs,
                                               const float* __restrict__ cw, const float* __restrict__ cb,
                                               const u16* __restrict__ Wt, const float* __restrict__ bias,
                                               u16* __restrict__ outb,
                                               int K, int Oout, int geglu_off) {
    __shared__ __align__(16) u16 As[64 * GP];
    __shared__ __align__(16) u16 Wsm[64 * GP];
    __shared__ __align__(16) u16 Wgm[64 * GP];
    const int t = threadIdx.x;
    const int w = t >> 6, lane = t & 63, c = lane & 15, quad = lane >> 4;
    const int o0 = blockIdx.x * 64, n0 = blockIdx.y * 64;
    const f4v zero = {0.f, 0.f, 0.f, 0.f};
    f4v acc[4]  = {zero, zero, zero, zero};
    f4v accg[4] = {zero, zero, zero, zero};
    const int nk = K >> 6;

    float fA[16];
    s8v wv0, wv1, gv0, gv1;

    auto loadWG = [&](int k0) {
        int i0 = t, i1 = t + 256;
        wv0 = *(const s8v*)(Wt + (size_t)(o0 + (i0 >> 3)) * K + k0 + (i0 & 7) * 8);
        wv1 = *(const s8v*)(Wt + (size_t)(o0 + (i1 >> 3)) * K + k0 + (i1 & 7) * 8);
        gv0 = *(const s8v*)(Wt + (size_t)(o0 + (i0 >> 3) + geglu_off) * K + k0 + (i0 & 7) * 8);
        gv1 = *(const s8v*)(Wt + (size_t)(o0 + (i1 >> 3) + geglu_off) * K + k0 + (i1 & 7) * 8);
    };
    auto storeWG = [&]() {
        int i0 = t, i1 = t + 256;
        *(s8v*)&Wsm[(i0 >> 3) * GP + (i0 & 7) * 8] = wv0;
        *(s8v*)&Wsm[(i1 >> 3) * GP + (i1 & 7) * 8] = wv1;
        *(s8v*)&Wgm[(i0 >> 3) * GP + (i0 & 7) * 8] = gv0;
        *(s8v*)&Wgm[(i1 >> 3) * GP + (i1 & 7) * 8] = gv1;
    };
    auto loadA = [&](int k0) {
        int r = t >> 2, s16 = (t & 3) * 16;
        int n = n0 + r;
        const float* src = A + (size_t)n * lda + k0 + s16;
        const float* cwp = cw + k0 + s16;
        const float* cbp = cb + k0 + s16;
        float m_ = mu[n], rr = rs[n];
#pragma unroll
        for (int i = 0; i < 16; ++i) fA[i] = (src[i] - m_) * rr * cwp[i] + cbp[i];
    };
    auto storeA = [&]() {
        int r = t >> 2, s16 = (t & 3) * 16;
        unsigned* dst = (unsigned*)&As[r * GP + s16];
#pragma unroll
        for (int i = 0; i < 8; ++i) dst[i] = pack2(fA[2 * i], fA[2 * i + 1]);
    };

    loadA(0); loadWG(0);
    storeA(); storeWG();
    __syncthreads();
    for (int k = 0; k < nk; ++k) {
        if (k + 1 < nk) { loadA((k + 1) << 6); loadWG((k + 1) << 6); }
        s8v a0 = *(const s8v*)&As[(w * 16 + c) * GP + quad * 8];
        s8v a1 = *(const s8v*)&As[(w * 16 + c) * GP + 32 + quad * 8];
#pragma unroll
        for (int nt = 0; nt < 4; ++nt) {
            s8v b0 = *(const s8v*)&Wsm[(nt * 16 + c) * GP + quad * 8];
            s8v b1 = *(const s8v*)&Wsm[(nt * 16 + c) * GP + 32 + quad * 8];
            acc[nt] = __builtin_amdgcn_mfma_f32_16x16x32_bf16(a0, b0, acc[nt], 0, 0, 0);
            acc[nt] = __builtin_amdgcn_mfma_f32_16x16x32_bf16(a1, b1, acc[nt], 0, 0, 0);
            s8v q0 = *(const s8v*)&Wgm[(nt * 16 + c) * GP + quad * 8];
            s8v q1 = *(const s8v*)&Wgm[(nt * 16 + c) * GP + 32 + quad * 8];
            accg[nt] = __builtin_amdgcn_mfma_f32_16x16x32_bf16(a0, q0, accg[nt], 0, 0, 0);
            accg[nt] = __builtin_amdgcn_mfma_f32_16x16x32_bf16(a1, q1, accg[nt], 0, 0, 0);
        }
        __syncthreads();
        if (k + 1 < nk) {
            storeA(); storeWG();
            __syncthreads();
        }
    }
#pragma unroll
    for (int nt = 0; nt < 4; ++nt) {
        int o = o0 + nt * 16 + c;
#pragma unroll
        for (int r = 0; r < 4; ++r) {
            int n = n0 + w * 16 + quad * 4 + r;
            float v = acc[nt][r] + bias[o];
            float gg = accg[nt][r] + bias[o + geglu_off];
            v = v * 0.5f * gg * (1.f + erff(gg * 0.70710678118654752f));
            outb[(size_t)n * Oout + o] = bf16u(v);
        }
    }
}

// ---------------- Self-attention v10b: 128-row Q-tile, 8 waves + XCD-aware block swizzle ----------
#define KSP 40
#define PSP 140
#define VP  136
__global__ __launch_bounds__(512) void attn_self10_k(const u16* __restrict__ qb, const u16* __restrict__ kb,
                                                     const u16* __restrict__ vt,
                                                     u16* __restrict__ Opart, float* __restrict__ lpart) {
    __shared__ __align__(16) u16 Ks[128 * KSP];   // 10240 B
    __shared__ __align__(16) u16 Ps[128 * PSP];   // 35840 B
    __shared__ __align__(16) u16 Vs[48 * VP];     // 13056 B
    const int t = threadIdx.x;
    const int w = t >> 6, lane = t & 63, c = lane & 15, quad = lane >> 4;
    // XCD swizzle: dispatch id -> logical (q-tile, head, ks); bijective over 512 = 8*64
    const int did = blockIdx.x + 32 * (blockIdx.y + 8 * blockIdx.z);
    const int lid = (did & 7) * 64 + (did >> 3);
    const int hd = (lid >> 5) & 7, ks = lid >> 8;
    const int q0 = (lid & 31) * 128;
    const f4v zero = {0.f, 0.f, 0.f, 0.f};
    const s8v z8 = {0, 0, 0, 0, 0, 0, 0, 0};

    // zero pad V rows 41..47; row 40 = 1.0 (PV-ones: col 40 of O accumulates sum(P) = l)
    for (int i = t; i < 8 * VP / 2; i += 512) ((unsigned*)&Vs[40 * VP])[i] = 0u;
    __syncthreads();
    if (t < VP) Vs[40 * VP + t] = (u16)0x3F80;

    const u16* qrow = qb + (size_t)(q0 + w * 16 + c) * DMODEL + hd * DHEAD;
    s8v qa0 = *(const s8v*)(qrow + quad * 8);
    s8v qa1 = z8;
    if (quad == 0) qa1 = *(const s8v*)(qrow + 32);

    // ---- staging: K = 640 s8v slots (128 rows x 5 segs), V = 640 slots (40 rows x 16 segs)
    const int i0 = t, i2 = t + 512;
    const int r0 = i0 / 5, s0 = i0 - r0 * 5;
    const int r2 = (t < 128) ? i2 / 5 : r0, s2 = (t < 128) ? (i2 - (i2 / 5) * 5) : s0;
    const u16* kq0 = kb + (size_t)(ks * 2048 + r0) * DMODEL + hd * DHEAD + s0 * 8;
    const u16* kq2 = kb + (size_t)(ks * 2048 + r2) * DMODEL + hd * DHEAD + s2 * 8;
    u16* ksd0 = &Ks[r0 * KSP + s0 * 8];
    u16* ksd2 = &Ks[r2 * KSP + s2 * 8];
    const int d0 = i0 >> 4, g0v = i0 & 15;
    const int d2 = (t < 128) ? (i2 >> 4) : d0, g2v = (t < 128) ? (i2 & 15) : g0v;
    const u16* vq0 = vt + (size_t)(hd * DHEAD + d0) * N_SEQ + ks * 2048 + g0v * 8;
    const u16* vq2 = vt + (size_t)(hd * DHEAD + d2) * N_SEQ + ks * 2048 + g2v * 8;
    u16* vsd0 = &Vs[d0 * VP + g0v * 8];
    u16* vsd2 = &Vs[d2 * VP + g2v * 8];
    const size_t kadv = (size_t)128 * DMODEL;

    // prologue: load tile 0 into regs
    s8v kA = *(const s8v*)kq0, kC = *(const s8v*)kq2;
    s8v vA = *(const s8v*)vq0, vC = *(const s8v*)vq2;
    kq0 += kadv; kq2 += kadv;
    vq0 += 128;  vq2 += 128;

    f4v o0 = zero, o1 = zero, o2 = zero;

    for (int kt = 0; kt < 16; ++kt) {
        __syncthreads();                       // previous tile fully consumed (K by QK^T, V by PV)
        *(s8v*)ksd0 = kA; *(s8v*)vsd0 = vA;
        if (t < 128) { *(s8v*)ksd2 = kC; *(s8v*)vsd2 = vC; }
        if (kt + 1 < 16) {                     // issue next-tile loads; latency overlaps compute below
            kA = *(const s8v*)kq0; vA = *(const s8v*)vq0;
            if (t < 128) { kC = *(const s8v*)kq2; vC = *(const s8v*)vq2; }
            kq0 += kadv; kq2 += kadv;
            vq0 += 128;  vq2 += 128;
        }
        __syncthreads();                       // staged tile visible

        f4v sarr[8];
#pragma unroll
        for (int nt = 0; nt < 8; ++nt) {
            const int kr = nt * 16 + c;
            s8v b0 = *(const s8v*)&Ks[kr * KSP + quad * 8];
            s8v b1 = z8;
            if (quad == 0) b1 = *(const s8v*)&Ks[kr * KSP + 32];
            f4v s = __builtin_amdgcn_mfma_f32_16x16x32_bf16(qa0, b0, zero, 0, 0, 0);
            s = __builtin_amdgcn_mfma_f32_16x16x32_bf16(qa1, b1, s, 0, 0, 0);
            sarr[nt] = s;
        }

        u16* psw = &Ps[(size_t)(w * 16 + quad * 4) * PSP + c];
#pragma unroll
        for (int reg = 0; reg < 8; ++reg) {
            const int colb = (reg >> 2) * 64 + (reg & 3) * 16;
#pragma unroll
            for (int r = 0; r < 4; ++r) {
                float pv = exp2f(sarr[reg][r]);   // Q pre-scaled by scale*log2e
                psw[r * PSP + colb] = (u16)(__float_as_uint(pv) >> 16);   // truncate
            }
        }

        const u16* prow = &Ps[(size_t)(w * 16 + c) * PSP];
#pragma unroll
        for (int h2 = 0; h2 < 2; ++h2) {
            s8v pa0, pa1;
            {
                s4v lo = *(const s4v*)(prow + h2 * 64 + quad * 8);
                s4v hi = *(const s4v*)(prow + h2 * 64 + quad * 8 + 4);
                pa0 = (s8v){lo[0], lo[1], lo[2], lo[3], hi[0], hi[1], hi[2], hi[3]};
                s4v lo2 = *(const s4v*)(prow + h2 * 64 + 32 + quad * 8);
                s4v hi2 = *(const s4v*)(prow + h2 * 64 + 32 + quad * 8 + 4);
                pa1 = (s8v){lo2[0], lo2[1], lo2[2], lo2[3], hi2[0], hi2[1], hi2[2], hi2[3]};
            }
            {
                s8v v0 = *(const s8v*)&Vs[(0 * 16 + c) * VP + h2 * 64 + quad * 8];
                s8v v1 = *(const s8v*)&Vs[(0 * 16 + c) * VP + h2 * 64 + 32 + quad * 8];
                o0 = __builtin_amdgcn_mfma_f32_16x16x32_bf16(pa0, v0, o0, 0, 0, 0);
                o0 = __builtin_amdgcn_mfma_f32_16x16x32_bf16(pa1, v1, o0, 0, 0, 0);
            }
            {
                s8v v0 = *(const s8v*)&Vs[(1 * 16 + c) * VP + h2 * 64 + quad * 8];
                s8v v1 = *(const s8v*)&Vs[(1 * 16 + c) * VP + h2 * 64 + 32 + quad * 8];
                o1 = __builtin_amdgcn_mfma_f32_16x16x32_bf16(pa0, v0, o1, 0, 0, 0);
                o1 = __builtin_amdgcn_mfma_f32_16x16x32_bf16(pa1, v1, o1, 0, 0, 0);
            }
            {
                s8v v0 = *(const s8v*)&Vs[(2 * 16 + c) * VP + h2 * 64 + quad * 8];
                s8v v1 = *(const s8v*)&Vs[(2 * 16 + c) * VP + h2 * 64 + 32 + quad * 8];
                o2 = __builtin_amdgcn_mfma_f32_16x16x32_bf16(pa0, v0, o2, 0, 0, 0);
                o2 = __builtin_amdgcn_mfma_f32_16x16x32_bf16(pa1, v1, o2, 0, 0, 0);
            }
        }
    }

    const size_t pb = (size_t)(ks * 8 + hd) * N_SEQ;
#pragma unroll
    for (int r = 0; r < 4; ++r) {
        int q = q0 + w * 16 + quad * 4 + r;
        u16* op = Opart + (pb + q) * DHEAD;
        op[c]      = bf16u(o0[r]);
        op[16 + c] = bf16u(o1[r]);
        if (c < 8) op[32 + c] = bf16u(o2[r]);
        if (c == 8) lpart[pb + q] = o2[r];   // col 40 = sum(P) via ones-row
    }
}

// ---------------- Cross-attention v3: MFMA tile kernel, 77 keys padded to 80/96 ----------------
__global__ __launch_bounds__(256) void attn_cross3_k(const u16* __restrict__ qb,   // [4096][320] bf16
                                                     const u16* __restrict__ kb,   // [77][320]  bf16
                                                     const u16* __restrict__ vt,   // [320][128] bf16 (cols>=77 garbage)
                                                     u16* __restrict__ outb) {     // [4096][320] bf16
    __shared__ __align__(16) u16 KsPs[64 * PSP];
    __shared__ __align__(16) u16 Vs[48 * VP];
    const int t = threadIdx.x;
    const int w = t >> 6, lane = t & 63, c = lane & 15, quad = lane >> 4;
    const int hd = blockIdx.y;
    const int q0 = blockIdx.x * 64;
    const float SC2 = 0.15811388300841897f * 1.4426950408889634f;
    const f4v zero = {0.f, 0.f, 0.f, 0.f};
    const s8v z8 = {0, 0, 0, 0, 0, 0, 0, 0};

    for (int i = t; i < 48 * VP / 2; i += 256) ((unsigned*)Vs)[i] = 0u;
    __syncthreads();
    if (t < VP) Vs[40 * VP + t] = (u16)0x3F80;        // ones row -> col 40 of O = sum(P) = l
    for (int i = t; i < 400; i += 256) {              // V: 40 d-rows x 10 chunks of 8 keys
        int d = i / 10, kc = i - d * 10;
        s8v v = *(const s8v*)(vt + (size_t)(hd * DHEAD + d) * 128 + kc * 8);
        if (kc == 9) { v[5] = 0; v[6] = 0; v[7] = 0; } // keys 77..79 garbage -> 0
        *(s8v*)&Vs[d * VP + kc * 8] = v;
    }
    for (int i = t; i < 385; i += 256) {              // K rows 0..76 (77..79 left garbage, masked later)
        int r = i / 5, sg = i - r * 5;
        *(s8v*)&KsPs[r * KSP + sg * 8] = *(const s8v*)(kb + (size_t)r * DMODEL + hd * DHEAD + sg * 8);
    }
    const u16* qrow = qb + (size_t)(q0 + w * 16 + c) * DMODEL + hd * DHEAD;
    s8v qa0 = *(const s8v*)(qrow + quad * 8);
    s8v qa1 = z8;
    if (quad == 0) qa1 = *(const s8v*)(qrow + 32);
    __syncthreads();

    f4v sarr[5];
#pragma unroll
    for (int nt = 0; nt < 5; ++nt) {
        const int kr = nt * 16 + c;
        s8v b0 = *(const s8v*)&KsPs[kr * KSP + quad * 8];
        s8v b1 = z8;
        if (quad == 0) b1 = *(const s8v*)&KsPs[kr * KSP + 32];
        f4v s = __builtin_amdgcn_mfma_f32_16x16x32_bf16(qa0, b0, zero, 0, 0, 0);
        s = __builtin_amdgcn_mfma_f32_16x16x32_bf16(qa1, b1, s, 0, 0, 0);
        sarr[nt] = s;
    }
    __syncthreads();   // all waves done reading K; reuse buffer for P

    u16* psw = &KsPs[(size_t)(w * 16 + quad * 4) * PSP + c];
#pragma unroll
    for (int r = 0; r < 4; ++r) {
        float s4 = (c < 13) ? sarr[4][r] : -1e30f;    // mask cols 77..79 (garbage K rows)
        float mx = fmaxf(fmaxf(fmaxf(sarr[0][r], sarr[1][r]), fmaxf(sarr[2][r], sarr[3][r])), s4);
        mx = fmaxf(mx, __shfl_xor(mx, 1));
        mx = fmaxf(mx, __shfl_xor(mx, 2));
        mx = fmaxf(mx, __shfl_xor(mx, 4));
        mx = fmaxf(mx, __shfl_xor(mx, 8));
#pragma unroll
        for (int nt = 0; nt < 4; ++nt)
            psw[r * PSP + nt * 16] = bf16u(exp2f((sarr[nt][r] - mx) * SC2));
        psw[r * PSP + 64] = (c < 13) ? bf16u(exp2f((s4 - mx) * SC2)) : (u16)0;
        psw[r * PSP + 80] = 0;                        // cols 80..95
    }

    const u16* prow = &KsPs[(size_t)(w * 16 + c) * PSP];
    f4v o0 = zero, o1 = zero, o2 = zero;
#pragma unroll
    for (int ch = 0; ch < 3; ++ch) {
        s4v lo = *(const s4v*)(prow + ch * 32 + quad * 8);
        s4v hi = *(const s4v*)(prow + ch * 32 + quad * 8 + 4);
        s8v pa = (s8v){lo[0], lo[1], lo[2], lo[3], hi[0], hi[1], hi[2], hi[3]};
        s8v v0 = *(const s8v*)&Vs[(0 * 16 + c) * VP + ch * 32 + quad * 8];
        o0 = __builtin_amdgcn_mfma_f32_16x16x32_bf16(pa, v0, o0, 0, 0, 0);
        s8v v1 = *(const s8v*)&Vs[(1 * 16 + c) * VP + ch * 32 + quad * 8];
        o1 = __builtin_amdgcn_mfma_f32_16x16x32_bf16(pa, v1, o1, 0, 0, 0);
        s8v v2 = *(const s8v*)&Vs[(2 * 16 + c) * VP + ch * 32 + quad * 8];
        o2 = __builtin_amdgcn_mfma_f32_16x16x32_bf16(pa, v2, o2, 0, 0, 0);
    }

#pragma unroll
    for (int r = 0; r < 4; ++r) {
        float inv = 1.f / __shfl(o2[r], (lane & 48) | 8);   // l lives at col 40 -> o2 tile, c==8
        int q = q0 + w * 16 + quad * 4 + r;
        u16* op = outb + (size_t)q * DMODEL + hd * DHEAD;
        op[c]      = bf16u(o0[r] * inv);
        op[16 + c] = bf16u(o1[r] * inv);
        if (c < 8) op[32 + c] = bf16u(o2[r] * inv);
    }
}

extern "C" void kernel_launch(void* const* d_in, const int* in_sizes, int n_in,
                              void* d_out, int out_size, void* d_ws, size_t ws_size,
                              hipStream_t stream) {
    const float* x      = (const float*)d_in[0];
    const float* ctx    = (const float*)d_in[1];
    const float* gn_w   = (const float*)d_in[2];
    const float* gn_b   = (const float*)d_in[3];
    const float* pin_w  = (const float*)d_in[4];
    const float* pin_b  = (const float*)d_in[5];
    const float* ln1_w  = (const float*)d_in[6];
    const float* ln1_b  = (const float*)d_in[7];
    const float* q1     = (const float*)d_in[8];
    const float* k1     = (const float*)d_in[9];
    const float* v1     = (const float*)d_in[10];
    const float* o1_w   = (const float*)d_in[11];
    const float* o1_b   = (const float*)d_in[12];
    const float* ln2_w  = (const float*)d_in[13];
    const float* ln2_b  = (const float*)d_in[14];
    const float* q2     = (const float*)d_in[15];
    const float* k2     = (const float*)d_in[16];
    const float* v2     = (const float*)d_in[17];
    const float* o2_w   = (const float*)d_in[18];
    const float* o2_b   = (const float*)d_in[19];
    const float* ln3_w  = (const float*)d_in[20];
    const float* ln3_b  = (const float*)d_in[21];
    const float* ff1_w  = (const float*)d_in[22];
    const float* ff1_b  = (const float*)d_in[23];
    const float* ff2_w  = (const float*)d_in[24];
    const float* ff2_b  = (const float*)d_in[25];
    const float* pout_w = (const float*)d_in[26];
    const float* pout_b = (const float*)d_in[27];
    float* out = (float*)d_out;

    char* base = (char*)d_ws;
    float* h     = (float*)(base);
    u16*   qb16  = (u16*)(base + 5242880);
    u16*   kb16  = (u16*)(base + 7864320);
    u16*   vt16  = (u16*)(base + 10485760);
    u16*   ao16  = (u16*)(base + 13107200);
    u16*   ffg16 = (u16*)(base + 5242880);
    u16*   wbase = (u16*)(base + 15728640);
    u16* pinT  = wbase;
    u16* q1T   = pinT  + 102400;
    u16* k1T   = q1T   + 102400;
    u16* v1T   = k1T   + 102400;
    u16* o1T   = v1T   + 102400;
    u16* q2T   = o1T   + 102400;
    u16* o2T   = q2T   + 102400;
    u16* k2T   = o2T   + 102400;
    u16* v2T   = k2T   + 245760;
    u16* ff1T  = v2T   + 245760;
    u16* ff2T  = ff1T  + 819200;
    u16* poutT = ff2T  + 409600;
    float* lnmu = (float*)(base + 20807680);
    float* lnrs = lnmu + 4096;
    u16*   k2b16 = (u16*)(lnrs + 4096);            // [77][320] bf16 keys
    u16*   v2t16 = (u16*)(lnrs + 4096 + 25600);    // [320][128] bf16 values (transposed, padded)
    u16*   Opart = (u16*)(lnrs + 4096 + 51200);
    float* lpart = (float*)(Opart + (size_t)2 * 8 * 4096 * 40);
    float* gnsc  = lpart + 2 * 8 * 4096;
    float* gnsh  = gnsc + 320;
    float* gpart = gnsh + 320;                     // 256 x 2 floats (GN partials)

    WCs wd;
    wd.a[0]  = {pin_w,  pinT,  320,  320,  0};
    wd.a[1]  = {q1,     q1T,   320,  320,  1};
    wd.a[2]  = {k1,     k1T,   320,  320,  1};
    wd.a[3]  = {v1,     v1T,   320,  320,  1};
    wd.a[4]  = {o1_w,   o1T,   320,  320,  1};
    wd.a[5]  = {q2,     q2T,   320,  320,  1};
    wd.a[6]  = {o2_w,   o2T,   320,  320,  1};
    wd.a[7]  = {k2,     k2T,   768,  320,  1};
    wd.a[8]  = {v2,     v2T,   768,  320,  1};
    wd.a[9]  = {ff1_w,  ff1T,  320,  2560, 1};
    wd.a[10] = {ff2_w,  ff2T,  1280, 320,  1};
    wd.a[11] = {pout_w, poutT, 320,  320,  0};
    wcast2_k<<<dim3(800, 12), 256, 0, stream>>>(wd);

    GArg gz = {nullptr, nullptr, nullptr, nullptr, 0};

    // 1. GN stats (2-stage, 256 blocks); proj_in (GN fused in staging)
    gn_part_k<<<256, 256, 0, stream>>>(x, gpart);
    gn_fin_k<<<1, 320, 0, stream>>>(gpart, gn_w, gn_b, gnsc, gnsh);
    {
        GArg g0 = {pinT, pin_b, h, nullptr, 0};
        gemm_t<0><<<dim3(5, 64, 1), 256, 0, stream>>>(x, 2, 4096, nullptr, nullptr, gnsc, gnsh,
                                                      g0, gz, gz, nullptr, 4096, 320, 320, 0);
    }
    // 2. qkv fused (LN1 in staging); Q written pre-scaled by scale*log2e
    ln_stats_k<<<1024, 256, 0, stream>>>(h, lnmu, lnrs);
    {
        GArg g0 = {q1T, nullptr, nullptr, qb16, 4};
        GArg g1 = {nullptr, nullptr, nullptr, kb16, 0};
        GArg g2 = {nullptr, nullptr, nullptr, vt16, 0};
        gemm_t<1><<<dim3(15, 64, 1), 256, 0, stream>>>(h, 3, 320, lnmu, lnrs, ln1_w, ln1_b,
                                                       g0, g1, g2, nullptr, 4096, 320, 960, 4096);
    }
    attn_self10_k<<<dim3(32, 8, 2), 512, 0, stream>>>(qb16, kb16, vt16, Opart, lpart);
    // 3. o1 proj: A = combined 2-split partials, residual h
    {
        GArg g0 = {o1T, o1_b, h, nullptr, 0};
        gemm_t<2><<<dim3(5, 64, 1), 256, 0, stream>>>(Opart, 4, 0, lpart, nullptr, nullptr, nullptr,
                                                      g0, gz, gz, h, 4096, 320, 320, 0);
    }
    // 4. cross-attention: q2 (z=0, LN2 in staging) + independent ctx K/V prep (z=1,2) in ONE launch
    ln_stats_k<<<1024, 256, 0, stream>>>(h, lnmu, lnrs);
    {
        GArg g0 = {q2T, nullptr, nullptr, qb16, 1};
        GArg g1 = {k2T, nullptr, nullptr, k2b16, 1};   // K -> bf16 rows [77][320]
        GArg g2 = {v2T, nullptr, nullptr, v2t16, 2};   // V -> bf16 transposed [320][128]
        gemm_t<3><<<dim3(5, 64, 3), 256, 0, stream>>>(h, 3, 320, lnmu, lnrs, ln2_w, ln2_b,
                                                      g0, g1, g2, ctx, 4096, 320, 320, 0);
    }
    attn_cross3_k<<<dim3(64, 8), 256, 0, stream>>>(qb16, k2b16, v2t16, ao16);
    {
        GArg g0 = {o2T, o2_b, h, nullptr, 0};
        gemm_t<5><<<dim3(5, 64, 1), 256, 0, stream>>>(ao16, 0, 320, nullptr, nullptr, nullptr, nullptr,
                                                      g0, gz, gz, h, 4096, 320, 320, 0);
    }
    // 5. GEGLU FF (LN3 in ff1 staging)
    ln_stats_k<<<1024, 256, 0, stream>>>(h, lnmu, lnrs);
    gemm_gg<<<dim3(20, 64, 1), 256, 0, stream>>>(h, 320, lnmu, lnrs, ln3_w, ln3_b,
                                                 ff1T, ff1_b, ffg16, 320, 1280, 1280);
    {
        GArg g0 = {ff2T, ff2_b, h, nullptr, 0};
        gemm_t<6><<<dim3(5, 64, 1), 256, 0, stream>>>(ffg16, 0, 1280, nullptr, nullptr, nullptr, nullptr,
                                                      g0, gz, gz, h, 4096, 1280, 320, 0);
    }
    // 6. proj_out + input residual
    {
        GArg g0 = {poutT, pout_b, out, nullptr, 3};
        gemm_t<7><<<dim3(5, 64, 1), 256, 0, stream>>>(h, 1, 320, nullptr, nullptr, nullptr, nullptr,
                                                      g0, gz, gz, x, 4096, 320, 320, 4096);
    }
}